// Round 18
// baseline (523.194 us; speedup 1.0000x reference)
//
#include <hip/hip_runtime.h>
#include <hip/hip_fp16.h>
#include <math.h>

// GCN 5-layer on MI355X — round 18:
//  (a) LDS-staged tile scatter (tile=4096): sort tile into LDS, then write
//      contiguous runs with consecutive lanes -> coalesced full lines.
//      Fixes R17's 3.3x write amplification + 13% occupancy in k_tscatter.
//  (b) agg64 packed-half math: nm decoded as raw half bits (q<<3, no cvt),
//      e5m2 pair expanded by byte shift, one v_pk_fma_f16 per edge.
// Rest as R17: 4B edge records {r:20,q12:12}, fp16 X, fp16-H gemm64 +
// k_pack -> e5m2 Hq, merged bsort with vfs scaling.

__device__ __forceinline__ float sigf(float x) { return 1.0f / (1.0f + expf(-x)); }

// decode two e5m2 bytes (lo=feat0, hi=feat1) -> float2 (non-hot paths)
__device__ __forceinline__ float2 bf8x2_to_float2(unsigned short v) {
  unsigned int h2 = ((unsigned int)(v & 0xff00u) << 16) | ((unsigned int)(v & 0x00ffu) << 8);
  __half2 h = *reinterpret_cast<__half2*>(&h2);
  return __half22float2(h);
}

// decode 12-bit e5m7 (positive) -> float (non-hot paths)
__device__ __forceinline__ float q12f(unsigned int q) {
  unsigned short hb = (unsigned short)(q << 3);
  __half h = *reinterpret_cast<__half*>(&hb);
  return __half2float(h);
}

#define RMASK 0xFFFFF
#define SUBS 8            // cursor streams per bucket (blockIdx & 7)
#define TILE_SHIFT 12     // 4096 edges per tile
#define TILE (1 << TILE_SHIFT)
#define NBMAX 512

__global__ __launch_bounds__(256) void k_count(const int* __restrict__ col,
                                               int* __restrict__ gcnt,
                                               int* __restrict__ gtile, int E, int NB) {
  __shared__ int lc[NBMAX];
  int t = threadIdx.x;
  for (int i = t; i < NB; i += 256) lc[i] = 0;
  __syncthreads();
  int base = blockIdx.x << TILE_SHIFT;
  int sub = blockIdx.x & (SUBS - 1);
  int hi = base + TILE; if (hi > E) hi = E;
  for (int e = base + t; e < hi; e += 256) atomicAdd(&lc[col[e] >> 8], 1);
  __syncthreads();
  size_t gt = (size_t)blockIdx.x * NB;
  for (int i = t; i < NB; i += 256) {
    int c = lc[i];
    gtile[gt + i] = c;
    if (c) atomicAdd(&gcnt[i * SUBS + sub], c);
  }
}

// scan M = NB*SUBS counters; cursors line-padded (16 ints apart)
__global__ __launch_bounds__(1024) void k_bscan(const int* __restrict__ gcnt,
                                                int* __restrict__ boff,
                                                int* __restrict__ bnextp,
                                                int* __restrict__ offn, int M, int N) {
  __shared__ int s[1024];
  int t = threadIdx.x;
  int chunk = (M + 1023) / 1024;
  int lo = t * chunk; if (lo > M) lo = M;
  int hi = lo + chunk; if (hi > M) hi = M;
  int sum = 0;
  for (int i = lo; i < hi; ++i) sum += gcnt[i];
  s[t] = sum;
  __syncthreads();
  for (int d = 1; d < 1024; d <<= 1) {
    int v = (t >= d) ? s[t - d] : 0;
    __syncthreads();
    s[t] += v;
    __syncthreads();
  }
  int run = s[t] - sum;
  for (int i = lo; i < hi; ++i) {
    boff[i] = run;
    bnextp[(size_t)i * 16] = run;
    run += gcnt[i];
  }
  if (t == 1023) { boff[M] = s[1023]; offn[N] = s[1023]; }
}

// LDS-staged tile scatter: sort tile (4096 edges) into LDS by bucket, then
// write contiguous runs with consecutive lanes (coalesced full lines).
__global__ __launch_bounds__(256) void k_tscatter(const int* __restrict__ row,
                                                  const int* __restrict__ col,
                                                  const float* __restrict__ w,
                                                  const int* __restrict__ gtile,
                                                  int* __restrict__ bnextp,
                                                  int2* __restrict__ raw, int E, int NB) {
  __shared__ int2 buf[TILE];            // 32 KB
  __shared__ unsigned short bkt[TILE];  // 8 KB
  __shared__ int loff[NBMAX];
  __shared__ int lc[NBMAX];
  __shared__ int shift[NBMAX];
  __shared__ int sc[256];
  int t = threadIdx.x;
  int e0 = blockIdx.x << TILE_SHIFT;
  int sub = blockIdx.x & (SUBS - 1);
  int e1 = e0 + TILE; if (e1 > E) e1 = E;
  size_t gt = (size_t)blockIdx.x * NB;
  // load per-tile counts (pairs for 512-entry scan with 256 threads)
  int c0 = (2 * t < NB) ? gtile[gt + 2 * t] : 0;
  int c1 = (2 * t + 1 < NB) ? gtile[gt + 2 * t + 1] : 0;
  sc[t] = c0 + c1;
  __syncthreads();
  for (int d = 1; d < 256; d <<= 1) {
    int v = (t >= d) ? sc[t - d] : 0;
    __syncthreads();
    sc[t] += v;
    __syncthreads();
  }
  int excl = sc[t] - (c0 + c1);
  if (2 * t < NB) { loff[2 * t] = excl; lc[2 * t] = 0; }
  if (2 * t + 1 < NB) { loff[2 * t + 1] = excl + c0; lc[2 * t + 1] = 0; }
  __syncthreads();
  // reserve global runs: one atomic per (tile,bucket)
  for (int i = t; i < NB; i += 256) {
    int c = (i < NB) ? ((i == 0) ? loff[1] - loff[0] + ((NB > 1) ? 0 : 0) : 0) : 0;
    (void)c;
  }
  for (int i = t; i < NB; i += 256) {
    int cnt = gtile[gt + i];
    int gb = cnt ? atomicAdd(&bnextp[(size_t)(i * SUBS + sub) * 16], cnt) : 0;
    shift[i] = gb - loff[i];
  }
  __syncthreads();
  // pass 2: sort edges into LDS
  for (int e = e0 + t; e < e1; e += 256) {
    int c = col[e];
    int b = c >> 8;
    int pl = loff[b] + atomicAdd(&lc[b], 1);
    buf[pl] = make_int2(row[e] | ((c & 255) << 20), __float_as_int(w[e]));
    bkt[pl] = (unsigned short)b;
  }
  __syncthreads();
  // pass 3: coalesced run writes
  int total = e1 - e0;
  for (int i = t; i < total; i += 256) {
    int b = bkt[i];
    raw[shift[b] + i] = buf[i];
  }
}

// Merged per-bucket counting sort: offn/dinv + vfs scaling + scatter
// edat = u32 {r:20, q12(w*dinv[c]):12}.
__global__ __launch_bounds__(256) void k_bsort(const int2* __restrict__ raw,
                                               const int* __restrict__ boff,
                                               const float* __restrict__ vf,
                                               unsigned int* __restrict__ edat,
                                               int* __restrict__ offn,
                                               float* __restrict__ dinv,
                                               float* __restrict__ vfs, int N) {
  __shared__ int cnt[256];
  __shared__ float wsum[256];
  __shared__ int s[256];
  __shared__ int pos[256];
  __shared__ float dl[256];
  int t = threadIdx.x, b = blockIdx.x;
  int e0 = boff[b * SUBS], e1 = boff[(b + 1) * SUBS];
  cnt[t] = 0;
  wsum[t] = 0.0f;
  __syncthreads();
  for (int e = e0 + t; e < e1; e += 256) {
    int2 a = raw[e];
    int cl = ((unsigned)a.x) >> 20;
    atomicAdd(&cnt[cl], 1);
    atomicAdd(&wsum[cl], __int_as_float(a.y));
  }
  __syncthreads();
  int c = cnt[t];
  s[t] = c;
  __syncthreads();
  for (int d = 1; d < 256; d <<= 1) {
    int v = (t >= d) ? s[t - d] : 0;
    __syncthreads();
    s[t] += v;
    __syncthreads();
  }
  int excl = s[t] - c;
  float dv = rsqrtf(wsum[t] + 1.0f);
  int node = b * 256 + t;
  if (node < N) {
    dinv[node] = dv;
    offn[node] = e0 + excl;
#pragma unroll
    for (int f = 0; f < 6; ++f) vfs[node * 6 + f] = dv * vf[node * 6 + f];
  }
  pos[t] = e0 + excl;
  dl[t] = dv;
  __syncthreads();
  for (int e = e0 + t; e < e1; e += 256) {
    int2 a = raw[e];
    int cl = ((unsigned)a.x) >> 20;
    float nrm = __int_as_float(a.y) * dl[cl];  // w * dinv[c], in (0,1)
    unsigned int q = ((unsigned int)__half_as_ushort(__float2half(nrm)) + 4u) >> 3;
    int p = atomicAdd(&pos[cl], 1);
    edat[p] = (unsigned int)(a.x & RMASK) | (q << 20);
  }
}

// Layer-1 aggregation on scaled features; 8 lanes/node; read-only.
__global__ __launch_bounds__(256) void k_agg6(const float* __restrict__ vfs,
                                              const float* __restrict__ dinv,
                                              const int* __restrict__ offn,
                                              const unsigned int* __restrict__ edat,
                                              float* __restrict__ Sx, int N) {
  int t = threadIdx.x, g = t >> 3, f = t & 7;
  int node = blockIdx.x * 32 + g;
  if (node >= N) return;
  bool act = f < 6;
  float dc = dinv[node];
  float acc = act ? dc * vfs[node * 6 + f] : 0.0f;  // dinv^2*vf = dinv*vfs
  int e1 = offn[node + 1];
  for (int e = offn[node]; e < e1; ++e) {
    unsigned int a = edat[e];
    if (act) acc += q12f(a >> 20) * vfs[(a & RMASK) * 6 + f];
  }
  if (act) Sx[node * 6 + f] = acc;
}

// X(half) = sigmoid(Sx @ W1 + b1), Sx [N,6], W1 [6,64]
__global__ __launch_bounds__(256) void k_gemm1(const float* __restrict__ Sx,
                                               const float* __restrict__ W1,
                                               const float* __restrict__ b1,
                                               __half* __restrict__ X, int N) {
  __shared__ float Wl[6 * 64];
  __shared__ float bl[64];
  __shared__ float XT[6 * 65];
  int t = threadIdx.x;
  int n0 = blockIdx.x * 64;
  for (int i = t; i < 384; i += 256) {
    Wl[i] = W1[i];
    int n = i / 6, k = i - n * 6;
    int node = n0 + n;
    XT[k * 65 + n] = (node < N) ? Sx[node * 6 + k] : 0.0f;
  }
  if (t < 64) bl[t] = b1[t];
  __syncthreads();
  int c0 = (t & 15) * 4;
  int nn = (t >> 4) * 4;
  float acc[4][4];
#pragma unroll
  for (int i = 0; i < 4; ++i)
#pragma unroll
    for (int j = 0; j < 4; ++j) acc[i][j] = bl[c0 + j];
#pragma unroll
  for (int k = 0; k < 6; ++k) {
    float4 wv = *(const float4*)&Wl[k * 64 + c0];
    float xv[4];
#pragma unroll
    for (int i = 0; i < 4; ++i) xv[i] = XT[k * 65 + nn + i];
#pragma unroll
    for (int i = 0; i < 4; ++i) {
      acc[i][0] += xv[i] * wv.x;
      acc[i][1] += xv[i] * wv.y;
      acc[i][2] += xv[i] * wv.z;
      acc[i][3] += xv[i] * wv.w;
    }
  }
#pragma unroll
  for (int i = 0; i < 4; ++i) {
    int node = n0 + nn + i;
    if (node < N) {
      __half2* dst = (__half2*)(X + (size_t)node * 64 + c0);
      dst[0] = __floats2half2_rn(sigf(acc[i][0]), sigf(acc[i][1]));
      dst[1] = __floats2half2_rn(sigf(acc[i][2]), sigf(acc[i][3]));
    }
  }
}

// H'(half) = dinv .* (X(half) @ W(f32)). 64x64 tile per block.
__global__ __launch_bounds__(256) void k_gemm64(const __half* __restrict__ Xin,
                                                const float* __restrict__ W,
                                                const float* __restrict__ dinv,
                                                __half* __restrict__ Hout, int N) {
  __shared__ float XT[64 * 65];
  __shared__ float Wl[64 * 64];
  int t = threadIdx.x;
  int n0 = blockIdx.x * 64;
#pragma unroll
  for (int i = 0; i < 4; ++i) {
    int idx = (i * 256 + t) * 4;
    *(float4*)&Wl[idx] = *(const float4*)&W[idx];
  }
#pragma unroll
  for (int i = 0; i < 2; ++i) {
    int idx = (i * 256 + t) * 8;
    int n = idx >> 6, k = idx & 63;
    int node = n0 + n;
    __half2 hv[4];
    if (node < N) {
      const __half2* src = (const __half2*)(Xin + (size_t)node * 64 + k);
      hv[0] = src[0]; hv[1] = src[1]; hv[2] = src[2]; hv[3] = src[3];
    } else {
      hv[0] = hv[1] = hv[2] = hv[3] = __floats2half2_rn(0.f, 0.f);
    }
#pragma unroll
    for (int j = 0; j < 4; ++j) {
      float2 f = __half22float2(hv[j]);
      XT[(k + 2 * j) * 65 + n] = f.x;
      XT[(k + 2 * j + 1) * 65 + n] = f.y;
    }
  }
  __syncthreads();
  int c0 = (t & 15) * 4;
  int nn = (t >> 4) * 4;
  float acc[4][4] = {{0.f}};
#pragma unroll
  for (int k = 0; k < 64; ++k) {
    float4 wv = *(const float4*)&Wl[k * 64 + c0];
    float xv[4];
#pragma unroll
    for (int i = 0; i < 4; ++i) xv[i] = XT[k * 65 + nn + i];
#pragma unroll
    for (int i = 0; i < 4; ++i) {
      acc[i][0] += xv[i] * wv.x;
      acc[i][1] += xv[i] * wv.y;
      acc[i][2] += xv[i] * wv.z;
      acc[i][3] += xv[i] * wv.w;
    }
  }
#pragma unroll
  for (int i = 0; i < 4; ++i) {
    int node = n0 + nn + i;
    if (node < N) {
      float dv = dinv[node];
      __half2* dst = (__half2*)(Hout + (size_t)node * 64 + c0);
      dst[0] = __floats2half2_rn(dv * acc[i][0], dv * acc[i][1]);
      dst[1] = __floats2half2_rn(dv * acc[i][2], dv * acc[i][3]);
    }
  }
}

// Streaming truncate: fp16 H' -> e5m2 Hq. 8 halves -> 8 bytes per thread.
__global__ __launch_bounds__(256) void k_pack(const __half* __restrict__ H,
                                              unsigned char* __restrict__ Hq,
                                              int total8) {
  int i = blockIdx.x * 256 + threadIdx.x;
  if (i >= total8) return;
  uint4 v = ((const uint4*)H)[i];  // 8 halves
  unsigned int lo, hi;
  {
    unsigned int a = ((v.x & 0xffffu) + 0x80u) >> 8;
    unsigned int b = (((v.x >> 16) & 0xffffu) + 0x80u) >> 8;
    unsigned int c = ((v.y & 0xffffu) + 0x80u) >> 8;
    unsigned int d = (((v.y >> 16) & 0xffffu) + 0x80u) >> 8;
    lo = (a & 0xffu) | ((b & 0xffu) << 8) | ((c & 0xffu) << 16) | ((d & 0xffu) << 24);
  }
  {
    unsigned int a = ((v.z & 0xffffu) + 0x80u) >> 8;
    unsigned int b = (((v.z >> 16) & 0xffffu) + 0x80u) >> 8;
    unsigned int c = ((v.w & 0xffffu) + 0x80u) >> 8;
    unsigned int d = (((v.w >> 16) & 0xffffu) + 0x80u) >> 8;
    hi = (a & 0xffu) | ((b & 0xffu) << 8) | ((c & 0xffu) << 16) | ((d & 0xffu) << 24);
  }
  ((uint2*)Hq)[i] = make_uint2(lo, hi);
}

// Half-wave-per-node CSC gather agg on e5m2 H'; lane owns features {2l,2l+1}.
// Packed-half math: 1 pk_fma per edge. LAST: h5' = dinv * (x . W5).
template <bool LAST>
__global__ __launch_bounds__(256) void k_agg64(const unsigned char* __restrict__ Hq,
                                               const float* __restrict__ dinv,
                                               const int* __restrict__ offn,
                                               const unsigned int* __restrict__ edat,
                                               const float* __restrict__ b,
                                               const float* __restrict__ W5,
                                               __half* __restrict__ Xout,
                                               float* __restrict__ h5, int N) {
  const unsigned short* Hh = (const unsigned short*)Hq;  // [N][32] e5m2x2
  int t = threadIdx.x;
  int l = t & 31;
  int hw = t >> 5;
  int node = blockIdx.x * 8 + hw;
  if (node >= N) return;
  float di = dinv[node];
  float2 sf = bf8x2_to_float2(Hh[(size_t)node * 32 + l]);
  __half2 acc = __floats2half2_rn(di * sf.x, di * sf.y);
  int e = offn[node], e1 = offn[node + 1];
  for (; e + 7 < e1; e += 8) {
    unsigned int a[8];
    unsigned short hv[8];
#pragma unroll
    for (int j = 0; j < 8; ++j) a[j] = edat[e + j];
#pragma unroll
    for (int j = 0; j < 8; ++j) hv[j] = Hh[(size_t)(a[j] & RMASK) * 32 + l];
#pragma unroll
    for (int j = 0; j < 8; ++j) {
      unsigned int nmb = ((a[j] >> 20) << 3) * 0x10001u;  // {nm,nm} half bits
      unsigned int hb = ((hv[j] & 0xffu) << 8) | (((unsigned int)hv[j] & 0xff00u) << 16);
      acc = __hfma2(*reinterpret_cast<__half2*>(&nmb),
                    *reinterpret_cast<__half2*>(&hb), acc);
    }
  }
  for (; e < e1; ++e) {
    unsigned int a = edat[e];
    unsigned short v = Hh[(size_t)(a & RMASK) * 32 + l];
    unsigned int nmb = ((a >> 20) << 3) * 0x10001u;
    unsigned int hb = ((v & 0xffu) << 8) | (((unsigned int)v & 0xff00u) << 16);
    acc = __hfma2(*reinterpret_cast<__half2*>(&nmb),
                  *reinterpret_cast<__half2*>(&hb), acc);
  }
  float2 fa = __half22float2(acc);
  float2 bb = ((const float2*)b)[l];
  float x0 = sigf(fa.x + bb.x);
  float x1 = sigf(fa.y + bb.y);
  if (LAST) {
    float2 w5 = ((const float2*)W5)[l];
    float v = x0 * w5.x + x1 * w5.y;
#pragma unroll
    for (int d = 16; d; d >>= 1) v += __shfl_xor(v, d);
    if (l == 0) h5[node] = di * v;  // h5' = dinv * (x . W5)
  } else {
    ((__half2*)(Xout + (size_t)node * 64))[l] = __floats2half2_rn(x0, x1);
  }
}

// scalar CSC aggregation on h5' + sigmoid + per-block partial sum
__global__ __launch_bounds__(256) void k_agg5(const float* __restrict__ h5,
                                              const float* __restrict__ dinv,
                                              const int* __restrict__ offn,
                                              const unsigned int* __restrict__ edat,
                                              const float* __restrict__ b5,
                                              float* __restrict__ partials, int N) {
  int n = blockIdx.x * 256 + threadIdx.x;
  float sig = 0.0f;
  if (n < N) {
    float di = dinv[n];
    float acc = di * h5[n];  // dinv^2 * (x.W5) = dinv * h5'
    int e1 = offn[n + 1];
    for (int e = offn[n]; e < e1; ++e) {
      unsigned int a = edat[e];
      acc += q12f(a >> 20) * h5[a & RMASK];
    }
    sig = sigf(acc + b5[0]);
  }
#pragma unroll
  for (int d = 32; d; d >>= 1) sig += __shfl_xor(sig, d);
  __shared__ float ws[4];
  int lane = threadIdx.x & 63, wid = threadIdx.x >> 6;
  if (lane == 0) ws[wid] = sig;
  __syncthreads();
  if (threadIdx.x == 0) partials[blockIdx.x] = ws[0] + ws[1] + ws[2] + ws[3];
}

__global__ __launch_bounds__(512) void k_final(const float* __restrict__ partials,
                                               float* __restrict__ out, int nb,
                                               float invN) {
  float v = 0.0f;
  for (int i = threadIdx.x; i < nb; i += 512) v += partials[i];
#pragma unroll
  for (int d = 32; d; d >>= 1) v += __shfl_xor(v, d);
  __shared__ float ws[8];
  int lane = threadIdx.x & 63, wid = threadIdx.x >> 6;
  if (lane == 0) ws[wid] = v;
  __syncthreads();
  if (threadIdx.x == 0) {
    float s = 0.0f;
    for (int i = 0; i < 8; ++i) s += ws[i];
    out[0] = s * invN;
  }
}

extern "C" void kernel_launch(void* const* d_in, const int* in_sizes, int n_in,
                              void* d_out, int out_size, void* d_ws, size_t ws_size,
                              hipStream_t stream) {
  const float* vf = (const float*)d_in[0];
  const int* edges = (const int*)d_in[1];
  const float* w = (const float*)d_in[2];
  const float* W1 = (const float*)d_in[3];
  const float* b1 = (const float*)d_in[4];
  const float* W2 = (const float*)d_in[5];
  const float* b2 = (const float*)d_in[6];
  const float* W3 = (const float*)d_in[7];
  const float* b3 = (const float*)d_in[8];
  const float* W4 = (const float*)d_in[9];
  const float* b4 = (const float*)d_in[10];
  const float* W5 = (const float*)d_in[11];
  const float* b5 = (const float*)d_in[12];
  float* out = (float*)d_out;

  const int N = in_sizes[0] / 6;
  const int E = in_sizes[2];
  const int* row = edges;
  const int* col = edges + E;
  const int NB = (N + 255) >> 8;
  const int M = NB * SUBS;
  const int tiles = (E + TILE - 1) >> TILE_SHIFT;

  size_t o = 0;
  auto carve = [&](size_t bytes) -> void* {
    void* p = (char*)d_ws + o;
    o += (bytes + 255) & ~(size_t)255;
    return p;
  };
  __half* X = (__half*)carve((size_t)N * 64 * 2);
  size_t hbytes = (size_t)N * 64 * 2;  // fp16 H'
  size_t rbytes = (size_t)E * 8;
  __half* H = (__half*)carve(hbytes > rbytes ? hbytes : rbytes);  // raw overlays H
  int2* raw = (int2*)H;
  unsigned char* Hq = (unsigned char*)carve((size_t)N * 64);  // e5m2 H'
  unsigned int* edat = (unsigned int*)carve((size_t)E * 4);   // {r:20, q12:12}
  float* Sx = (float*)carve((size_t)N * 6 * 4);
  float* vfs = (float*)carve((size_t)N * 6 * 4);
  float* dinv = (float*)carve((size_t)N * 4);
  int* boff = (int*)carve((size_t)(M + 1) * 4);
  int* bnextp = (int*)carve((size_t)M * 16 * 4);  // line-padded cursors
  int* gcnt = (int*)carve((size_t)M * 4);
  int* gtile = (int*)carve((size_t)tiles * NB * 4);
  int* offn = (int*)carve((size_t)(N + 1) * 4);
  float* h5 = (float*)carve((size_t)N * 4);
  const int nb5 = (N + 255) / 256;
  float* partials = (float*)carve((size_t)nb5 * 4);

  hipMemsetAsync(gcnt, 0, (size_t)M * 4, stream);

  k_count<<<tiles, 256, 0, stream>>>(col, gcnt, gtile, E, NB);
  k_bscan<<<1, 1024, 0, stream>>>(gcnt, boff, bnextp, offn, M, N);
  k_tscatter<<<tiles, 256, 0, stream>>>(row, col, w, gtile, bnextp, raw, E, NB);
  k_bsort<<<NB, 256, 0, stream>>>(raw, boff, vf, edat, offn, dinv, vfs, N);

  // layer 1: aggregate (D=6) on scaled features, dense 6->64 (fp16 X out)
  k_agg6<<<(N + 31) / 32, 256, 0, stream>>>(vfs, dinv, offn, edat, Sx, N);
  k_gemm1<<<(N + 63) / 64, 256, 0, stream>>>(Sx, W1, b1, X, N);

  // layers 2-4: gemm64 (fp16 H') -> pack (e5m2) -> agg64 (fp8 gather)
  const int nbA = (N + 7) / 8;
  const int total8 = N * 8;  // N*64/8 vec-units
  const int pb = (total8 + 255) / 256;
  k_gemm64<<<(N + 63) / 64, 256, 0, stream>>>(X, W2, dinv, H, N);
  k_pack<<<pb, 256, 0, stream>>>(H, Hq, total8);
  k_agg64<false><<<nbA, 256, 0, stream>>>(Hq, dinv, offn, edat, b2, W5, X, h5, N);
  k_gemm64<<<(N + 63) / 64, 256, 0, stream>>>(X, W3, dinv, H, N);
  k_pack<<<pb, 256, 0, stream>>>(H, Hq, total8);
  k_agg64<false><<<nbA, 256, 0, stream>>>(Hq, dinv, offn, edat, b3, W5, X, h5, N);
  k_gemm64<<<(N + 63) / 64, 256, 0, stream>>>(X, W4, dinv, H, N);
  k_pack<<<pb, 256, 0, stream>>>(H, Hq, total8);
  k_agg64<true><<<nbA, 256, 0, stream>>>(Hq, dinv, offn, edat, b4, W5, X, h5, N);

  // layer 5: scalar aggregation + mean
  k_agg5<<<nb5, 256, 0, stream>>>(h5, dinv, offn, edat, b5, partials, N);
  k_final<<<1, 512, 0, stream>>>(partials, out, nb5, 1.0f / (float)N);
}

// Round 19
// 479.198 us; speedup vs baseline: 1.0918x; 1.0918x over previous
//
#include <hip/hip_runtime.h>
#include <hip/hip_fp16.h>
#include <math.h>

// GCN 5-layer on MI355X — round 19: quarter-wave agg64.
// R18 lesson: agg64 still VALU-bound (71% busy) — decode duplicated across
// 32 lanes + 64-bit addr math. Fix: 16 lanes/node (lane owns 4 features =
// one uint of the 64B fp8 row), v_perm expands 4 e5m2 bytes -> 2 half2 in
// 2 ops, 32-bit indices -> saddr loads. Lane-edges halve; ~160 lane-ops/edge.
// Rest as R18: LDS tile scatter, 4B edges {r:20,q12:12}, fp16 X, fp16-H
// gemm64 + k_pack -> e5m2 Hq, merged bsort with vfs scaling.

__device__ __forceinline__ float sigf(float x) { return 1.0f / (1.0f + expf(-x)); }

// decode two e5m2 bytes (lo=feat0, hi=feat1) -> float2 (non-hot paths)
__device__ __forceinline__ float2 bf8x2_to_float2(unsigned short v) {
  unsigned int h2 = ((unsigned int)(v & 0xff00u) << 16) | ((unsigned int)(v & 0x00ffu) << 8);
  __half2 h = *reinterpret_cast<__half2*>(&h2);
  return __half22float2(h);
}

// decode 12-bit e5m7 (positive) -> float (non-hot paths)
__device__ __forceinline__ float q12f(unsigned int q) {
  unsigned short hb = (unsigned short)(q << 3);
  __half h = *reinterpret_cast<__half*>(&hb);
  return __half2float(h);
}

#define RMASK 0xFFFFF
#define SUBS 8            // cursor streams per bucket (blockIdx & 7)
#define TILE_SHIFT 12     // 4096 edges per tile
#define TILE (1 << TILE_SHIFT)
#define NBMAX 512

__global__ __launch_bounds__(256) void k_count(const int* __restrict__ col,
                                               int* __restrict__ gcnt,
                                               int* __restrict__ gtile, int E, int NB) {
  __shared__ int lc[NBMAX];
  int t = threadIdx.x;
  for (int i = t; i < NB; i += 256) lc[i] = 0;
  __syncthreads();
  int base = blockIdx.x << TILE_SHIFT;
  int sub = blockIdx.x & (SUBS - 1);
  int hi = base + TILE; if (hi > E) hi = E;
  for (int e = base + t; e < hi; e += 256) atomicAdd(&lc[col[e] >> 8], 1);
  __syncthreads();
  size_t gt = (size_t)blockIdx.x * NB;
  for (int i = t; i < NB; i += 256) {
    int c = lc[i];
    gtile[gt + i] = c;
    if (c) atomicAdd(&gcnt[i * SUBS + sub], c);
  }
}

// scan M = NB*SUBS counters; cursors line-padded (16 ints apart)
__global__ __launch_bounds__(1024) void k_bscan(const int* __restrict__ gcnt,
                                                int* __restrict__ boff,
                                                int* __restrict__ bnextp,
                                                int* __restrict__ offn, int M, int N) {
  __shared__ int s[1024];
  int t = threadIdx.x;
  int chunk = (M + 1023) / 1024;
  int lo = t * chunk; if (lo > M) lo = M;
  int hi = lo + chunk; if (hi > M) hi = M;
  int sum = 0;
  for (int i = lo; i < hi; ++i) sum += gcnt[i];
  s[t] = sum;
  __syncthreads();
  for (int d = 1; d < 1024; d <<= 1) {
    int v = (t >= d) ? s[t - d] : 0;
    __syncthreads();
    s[t] += v;
    __syncthreads();
  }
  int run = s[t] - sum;
  for (int i = lo; i < hi; ++i) {
    boff[i] = run;
    bnextp[(size_t)i * 16] = run;
    run += gcnt[i];
  }
  if (t == 1023) { boff[M] = s[1023]; offn[N] = s[1023]; }
}

// LDS-staged tile scatter: sort tile (4096 edges) into LDS by bucket, then
// write contiguous runs with consecutive lanes (coalesced full lines).
__global__ __launch_bounds__(256) void k_tscatter(const int* __restrict__ row,
                                                  const int* __restrict__ col,
                                                  const float* __restrict__ w,
                                                  const int* __restrict__ gtile,
                                                  int* __restrict__ bnextp,
                                                  int2* __restrict__ raw, int E, int NB) {
  __shared__ int2 buf[TILE];            // 32 KB
  __shared__ unsigned short bkt[TILE];  // 8 KB
  __shared__ int loff[NBMAX];
  __shared__ int lc[NBMAX];
  __shared__ int shift[NBMAX];
  __shared__ int sc[256];
  int t = threadIdx.x;
  int e0 = blockIdx.x << TILE_SHIFT;
  int sub = blockIdx.x & (SUBS - 1);
  int e1 = e0 + TILE; if (e1 > E) e1 = E;
  size_t gt = (size_t)blockIdx.x * NB;
  // load per-tile counts (pairs for 512-entry scan with 256 threads)
  int c0 = (2 * t < NB) ? gtile[gt + 2 * t] : 0;
  int c1 = (2 * t + 1 < NB) ? gtile[gt + 2 * t + 1] : 0;
  sc[t] = c0 + c1;
  __syncthreads();
  for (int d = 1; d < 256; d <<= 1) {
    int v = (t >= d) ? sc[t - d] : 0;
    __syncthreads();
    sc[t] += v;
    __syncthreads();
  }
  int excl = sc[t] - (c0 + c1);
  if (2 * t < NB) { loff[2 * t] = excl; lc[2 * t] = 0; }
  if (2 * t + 1 < NB) { loff[2 * t + 1] = excl + c0; lc[2 * t + 1] = 0; }
  __syncthreads();
  // reserve global runs: one atomic per (tile,bucket)
  for (int i = t; i < NB; i += 256) {
    int cnt = gtile[gt + i];
    int gb = cnt ? atomicAdd(&bnextp[(size_t)(i * SUBS + sub) * 16], cnt) : 0;
    shift[i] = gb - loff[i];
  }
  __syncthreads();
  // pass 2: sort edges into LDS
  for (int e = e0 + t; e < e1; e += 256) {
    int c = col[e];
    int b = c >> 8;
    int pl = loff[b] + atomicAdd(&lc[b], 1);
    buf[pl] = make_int2(row[e] | ((c & 255) << 20), __float_as_int(w[e]));
    bkt[pl] = (unsigned short)b;
  }
  __syncthreads();
  // pass 3: coalesced run writes
  int total = e1 - e0;
  for (int i = t; i < total; i += 256) {
    int b = bkt[i];
    raw[shift[b] + i] = buf[i];
  }
}

// Merged per-bucket counting sort: offn/dinv + vfs scaling + scatter
// edat = u32 {r:20, q12(w*dinv[c]):12}.
__global__ __launch_bounds__(256) void k_bsort(const int2* __restrict__ raw,
                                               const int* __restrict__ boff,
                                               const float* __restrict__ vf,
                                               unsigned int* __restrict__ edat,
                                               int* __restrict__ offn,
                                               float* __restrict__ dinv,
                                               float* __restrict__ vfs, int N) {
  __shared__ int cnt[256];
  __shared__ float wsum[256];
  __shared__ int s[256];
  __shared__ int pos[256];
  __shared__ float dl[256];
  int t = threadIdx.x, b = blockIdx.x;
  int e0 = boff[b * SUBS], e1 = boff[(b + 1) * SUBS];
  cnt[t] = 0;
  wsum[t] = 0.0f;
  __syncthreads();
  for (int e = e0 + t; e < e1; e += 256) {
    int2 a = raw[e];
    int cl = ((unsigned)a.x) >> 20;
    atomicAdd(&cnt[cl], 1);
    atomicAdd(&wsum[cl], __int_as_float(a.y));
  }
  __syncthreads();
  int c = cnt[t];
  s[t] = c;
  __syncthreads();
  for (int d = 1; d < 256; d <<= 1) {
    int v = (t >= d) ? s[t - d] : 0;
    __syncthreads();
    s[t] += v;
    __syncthreads();
  }
  int excl = s[t] - c;
  float dv = rsqrtf(wsum[t] + 1.0f);
  int node = b * 256 + t;
  if (node < N) {
    dinv[node] = dv;
    offn[node] = e0 + excl;
#pragma unroll
    for (int f = 0; f < 6; ++f) vfs[node * 6 + f] = dv * vf[node * 6 + f];
  }
  pos[t] = e0 + excl;
  dl[t] = dv;
  __syncthreads();
  for (int e = e0 + t; e < e1; e += 256) {
    int2 a = raw[e];
    int cl = ((unsigned)a.x) >> 20;
    float nrm = __int_as_float(a.y) * dl[cl];  // w * dinv[c], in (0,1)
    unsigned int q = ((unsigned int)__half_as_ushort(__float2half(nrm)) + 4u) >> 3;
    int p = atomicAdd(&pos[cl], 1);
    edat[p] = (unsigned int)(a.x & RMASK) | (q << 20);
  }
}

// Layer-1 aggregation on scaled features; 8 lanes/node; read-only.
__global__ __launch_bounds__(256) void k_agg6(const float* __restrict__ vfs,
                                              const float* __restrict__ dinv,
                                              const int* __restrict__ offn,
                                              const unsigned int* __restrict__ edat,
                                              float* __restrict__ Sx, int N) {
  int t = threadIdx.x, g = t >> 3, f = t & 7;
  int node = blockIdx.x * 32 + g;
  if (node >= N) return;
  bool act = f < 6;
  float dc = dinv[node];
  float acc = act ? dc * vfs[node * 6 + f] : 0.0f;  // dinv^2*vf = dinv*vfs
  int e1 = offn[node + 1];
  for (int e = offn[node]; e < e1; ++e) {
    unsigned int a = edat[e];
    if (act) acc += q12f(a >> 20) * vfs[(a & RMASK) * 6 + f];
  }
  if (act) Sx[node * 6 + f] = acc;
}

// X(half) = sigmoid(Sx @ W1 + b1), Sx [N,6], W1 [6,64]
__global__ __launch_bounds__(256) void k_gemm1(const float* __restrict__ Sx,
                                               const float* __restrict__ W1,
                                               const float* __restrict__ b1,
                                               __half* __restrict__ X, int N) {
  __shared__ float Wl[6 * 64];
  __shared__ float bl[64];
  __shared__ float XT[6 * 65];
  int t = threadIdx.x;
  int n0 = blockIdx.x * 64;
  for (int i = t; i < 384; i += 256) {
    Wl[i] = W1[i];
    int n = i / 6, k = i - n * 6;
    int node = n0 + n;
    XT[k * 65 + n] = (node < N) ? Sx[node * 6 + k] : 0.0f;
  }
  if (t < 64) bl[t] = b1[t];
  __syncthreads();
  int c0 = (t & 15) * 4;
  int nn = (t >> 4) * 4;
  float acc[4][4];
#pragma unroll
  for (int i = 0; i < 4; ++i)
#pragma unroll
    for (int j = 0; j < 4; ++j) acc[i][j] = bl[c0 + j];
#pragma unroll
  for (int k = 0; k < 6; ++k) {
    float4 wv = *(const float4*)&Wl[k * 64 + c0];
    float xv[4];
#pragma unroll
    for (int i = 0; i < 4; ++i) xv[i] = XT[k * 65 + nn + i];
#pragma unroll
    for (int i = 0; i < 4; ++i) {
      acc[i][0] += xv[i] * wv.x;
      acc[i][1] += xv[i] * wv.y;
      acc[i][2] += xv[i] * wv.z;
      acc[i][3] += xv[i] * wv.w;
    }
  }
#pragma unroll
  for (int i = 0; i < 4; ++i) {
    int node = n0 + nn + i;
    if (node < N) {
      __half2* dst = (__half2*)(X + (size_t)node * 64 + c0);
      dst[0] = __floats2half2_rn(sigf(acc[i][0]), sigf(acc[i][1]));
      dst[1] = __floats2half2_rn(sigf(acc[i][2]), sigf(acc[i][3]));
    }
  }
}

// H'(half) = dinv .* (X(half) @ W(f32)). 64x64 tile per block.
__global__ __launch_bounds__(256) void k_gemm64(const __half* __restrict__ Xin,
                                                const float* __restrict__ W,
                                                const float* __restrict__ dinv,
                                                __half* __restrict__ Hout, int N) {
  __shared__ float XT[64 * 65];
  __shared__ float Wl[64 * 64];
  int t = threadIdx.x;
  int n0 = blockIdx.x * 64;
#pragma unroll
  for (int i = 0; i < 4; ++i) {
    int idx = (i * 256 + t) * 4;
    *(float4*)&Wl[idx] = *(const float4*)&W[idx];
  }
#pragma unroll
  for (int i = 0; i < 2; ++i) {
    int idx = (i * 256 + t) * 8;
    int n = idx >> 6, k = idx & 63;
    int node = n0 + n;
    __half2 hv[4];
    if (node < N) {
      const __half2* src = (const __half2*)(Xin + (size_t)node * 64 + k);
      hv[0] = src[0]; hv[1] = src[1]; hv[2] = src[2]; hv[3] = src[3];
    } else {
      hv[0] = hv[1] = hv[2] = hv[3] = __floats2half2_rn(0.f, 0.f);
    }
#pragma unroll
    for (int j = 0; j < 4; ++j) {
      float2 f = __half22float2(hv[j]);
      XT[(k + 2 * j) * 65 + n] = f.x;
      XT[(k + 2 * j + 1) * 65 + n] = f.y;
    }
  }
  __syncthreads();
  int c0 = (t & 15) * 4;
  int nn = (t >> 4) * 4;
  float acc[4][4] = {{0.f}};
#pragma unroll
  for (int k = 0; k < 64; ++k) {
    float4 wv = *(const float4*)&Wl[k * 64 + c0];
    float xv[4];
#pragma unroll
    for (int i = 0; i < 4; ++i) xv[i] = XT[k * 65 + nn + i];
#pragma unroll
    for (int i = 0; i < 4; ++i) {
      acc[i][0] += xv[i] * wv.x;
      acc[i][1] += xv[i] * wv.y;
      acc[i][2] += xv[i] * wv.z;
      acc[i][3] += xv[i] * wv.w;
    }
  }
#pragma unroll
  for (int i = 0; i < 4; ++i) {
    int node = n0 + nn + i;
    if (node < N) {
      float dv = dinv[node];
      __half2* dst = (__half2*)(Hout + (size_t)node * 64 + c0);
      dst[0] = __floats2half2_rn(dv * acc[i][0], dv * acc[i][1]);
      dst[1] = __floats2half2_rn(dv * acc[i][2], dv * acc[i][3]);
    }
  }
}

// Streaming truncate: fp16 H' -> e5m2 Hq. 8 halves -> 8 bytes per thread.
__global__ __launch_bounds__(256) void k_pack(const __half* __restrict__ H,
                                              unsigned char* __restrict__ Hq,
                                              int total8) {
  int i = blockIdx.x * 256 + threadIdx.x;
  if (i >= total8) return;
  uint4 v = ((const uint4*)H)[i];  // 8 halves
  unsigned int lo, hi;
  {
    unsigned int a = ((v.x & 0xffffu) + 0x80u) >> 8;
    unsigned int b = (((v.x >> 16) & 0xffffu) + 0x80u) >> 8;
    unsigned int c = ((v.y & 0xffffu) + 0x80u) >> 8;
    unsigned int d = (((v.y >> 16) & 0xffffu) + 0x80u) >> 8;
    lo = (a & 0xffu) | ((b & 0xffu) << 8) | ((c & 0xffu) << 16) | ((d & 0xffu) << 24);
  }
  {
    unsigned int a = ((v.z & 0xffffu) + 0x80u) >> 8;
    unsigned int b = (((v.z >> 16) & 0xffffu) + 0x80u) >> 8;
    unsigned int c = ((v.w & 0xffffu) + 0x80u) >> 8;
    unsigned int d = (((v.w >> 16) & 0xffffu) + 0x80u) >> 8;
    hi = (a & 0xffu) | ((b & 0xffu) << 8) | ((c & 0xffu) << 16) | ((d & 0xffu) << 24);
  }
  ((uint2*)Hq)[i] = make_uint2(lo, hi);
}

// Quarter-wave-per-node CSC gather agg on e5m2 H'; lane owns feats {4l..4l+3}.
// v_perm expands 4 e5m2 bytes -> 2 half2; 2 pk_fma per edge.
// LAST: h5' = dinv * (x . W5).
template <bool LAST>
__global__ __launch_bounds__(256) void k_agg64(const unsigned char* __restrict__ Hq,
                                               const float* __restrict__ dinv,
                                               const int* __restrict__ offn,
                                               const unsigned int* __restrict__ edat,
                                               const float* __restrict__ b,
                                               const float* __restrict__ W5,
                                               __half* __restrict__ Xout,
                                               float* __restrict__ h5, int N) {
  const unsigned int* Hu = (const unsigned int*)Hq;  // [N][16] e5m2x4
  const unsigned int sel0 = 0x01040004u;  // {0, b0, 0, b1} from lo operand
  const unsigned int sel1 = 0x03040204u;  // {0, b2, 0, b3}
  int t = threadIdx.x;
  int l = t & 15;
  int qw = t >> 4;  // 16 quarter-waves per block
  int node = blockIdx.x * 16 + qw;
  if (node >= N) return;
  float di = dinv[node];
  unsigned int sh = Hu[(unsigned int)node * 16 + l];
  unsigned int sb0 = __builtin_amdgcn_perm(0u, sh, sel0);
  unsigned int sb1 = __builtin_amdgcn_perm(0u, sh, sel1);
  float2 f01 = __half22float2(*reinterpret_cast<__half2*>(&sb0));
  float2 f23 = __half22float2(*reinterpret_cast<__half2*>(&sb1));
  __half2 acc0 = __floats2half2_rn(di * f01.x, di * f01.y);
  __half2 acc1 = __floats2half2_rn(di * f23.x, di * f23.y);
  int e = offn[node], e1 = offn[node + 1];
  for (; e + 7 < e1; e += 8) {
    unsigned int a[8];
    unsigned int hv[8];
#pragma unroll
    for (int j = 0; j < 8; ++j) a[j] = edat[e + j];
#pragma unroll
    for (int j = 0; j < 8; ++j) hv[j] = Hu[(a[j] & RMASK) * 16u + l];
#pragma unroll
    for (int j = 0; j < 8; ++j) {
      unsigned int nmb = ((a[j] >> 20) << 3) * 0x10001u;  // {nm,nm} half bits
      unsigned int hb0 = __builtin_amdgcn_perm(0u, hv[j], sel0);
      unsigned int hb1 = __builtin_amdgcn_perm(0u, hv[j], sel1);
      acc0 = __hfma2(*reinterpret_cast<__half2*>(&nmb),
                     *reinterpret_cast<__half2*>(&hb0), acc0);
      acc1 = __hfma2(*reinterpret_cast<__half2*>(&nmb),
                     *reinterpret_cast<__half2*>(&hb1), acc1);
    }
  }
  for (; e < e1; ++e) {
    unsigned int a = edat[e];
    unsigned int hv = Hu[(a & RMASK) * 16u + l];
    unsigned int nmb = ((a >> 20) << 3) * 0x10001u;
    unsigned int hb0 = __builtin_amdgcn_perm(0u, hv, sel0);
    unsigned int hb1 = __builtin_amdgcn_perm(0u, hv, sel1);
    acc0 = __hfma2(*reinterpret_cast<__half2*>(&nmb),
                   *reinterpret_cast<__half2*>(&hb0), acc0);
    acc1 = __hfma2(*reinterpret_cast<__half2*>(&nmb),
                   *reinterpret_cast<__half2*>(&hb1), acc1);
  }
  float2 a01 = __half22float2(acc0);
  float2 a23 = __half22float2(acc1);
  float4 bb = ((const float4*)b)[l];
  float x0 = sigf(a01.x + bb.x);
  float x1 = sigf(a01.y + bb.y);
  float x2 = sigf(a23.x + bb.z);
  float x3 = sigf(a23.y + bb.w);
  if (LAST) {
    float4 w5 = ((const float4*)W5)[l];
    float v = x0 * w5.x + x1 * w5.y + x2 * w5.z + x3 * w5.w;
#pragma unroll
    for (int d = 8; d; d >>= 1) v += __shfl_xor(v, d);  // within quarter-wave
    if (l == 0) h5[node] = di * v;  // h5' = dinv * (x . W5)
  } else {
    __half2 o0 = __floats2half2_rn(x0, x1);
    __half2 o1 = __floats2half2_rn(x2, x3);
    ((uint2*)(Xout + (size_t)node * 64))[l] =
        make_uint2(*reinterpret_cast<unsigned int*>(&o0),
                   *reinterpret_cast<unsigned int*>(&o1));
  }
}

// scalar CSC aggregation on h5' + sigmoid + per-block partial sum
__global__ __launch_bounds__(256) void k_agg5(const float* __restrict__ h5,
                                              const float* __restrict__ dinv,
                                              const int* __restrict__ offn,
                                              const unsigned int* __restrict__ edat,
                                              const float* __restrict__ b5,
                                              float* __restrict__ partials, int N) {
  int n = blockIdx.x * 256 + threadIdx.x;
  float sig = 0.0f;
  if (n < N) {
    float di = dinv[n];
    float acc = di * h5[n];  // dinv^2 * (x.W5) = dinv * h5'
    int e1 = offn[n + 1];
    for (int e = offn[n]; e < e1; ++e) {
      unsigned int a = edat[e];
      acc += q12f(a >> 20) * h5[a & RMASK];
    }
    sig = sigf(acc + b5[0]);
  }
#pragma unroll
  for (int d = 32; d; d >>= 1) sig += __shfl_xor(sig, d);
  __shared__ float ws[4];
  int lane = threadIdx.x & 63, wid = threadIdx.x >> 6;
  if (lane == 0) ws[wid] = sig;
  __syncthreads();
  if (threadIdx.x == 0) partials[blockIdx.x] = ws[0] + ws[1] + ws[2] + ws[3];
}

__global__ __launch_bounds__(512) void k_final(const float* __restrict__ partials,
                                               float* __restrict__ out, int nb,
                                               float invN) {
  float v = 0.0f;
  for (int i = threadIdx.x; i < nb; i += 512) v += partials[i];
#pragma unroll
  for (int d = 32; d; d >>= 1) v += __shfl_xor(v, d);
  __shared__ float ws[8];
  int lane = threadIdx.x & 63, wid = threadIdx.x >> 6;
  if (lane == 0) ws[wid] = v;
  __syncthreads();
  if (threadIdx.x == 0) {
    float s = 0.0f;
    for (int i = 0; i < 8; ++i) s += ws[i];
    out[0] = s * invN;
  }
}

extern "C" void kernel_launch(void* const* d_in, const int* in_sizes, int n_in,
                              void* d_out, int out_size, void* d_ws, size_t ws_size,
                              hipStream_t stream) {
  const float* vf = (const float*)d_in[0];
  const int* edges = (const int*)d_in[1];
  const float* w = (const float*)d_in[2];
  const float* W1 = (const float*)d_in[3];
  const float* b1 = (const float*)d_in[4];
  const float* W2 = (const float*)d_in[5];
  const float* b2 = (const float*)d_in[6];
  const float* W3 = (const float*)d_in[7];
  const float* b3 = (const float*)d_in[8];
  const float* W4 = (const float*)d_in[9];
  const float* b4 = (const float*)d_in[10];
  const float* W5 = (const float*)d_in[11];
  const float* b5 = (const float*)d_in[12];
  float* out = (float*)d_out;

  const int N = in_sizes[0] / 6;
  const int E = in_sizes[2];
  const int* row = edges;
  const int* col = edges + E;
  const int NB = (N + 255) >> 8;
  const int M = NB * SUBS;
  const int tiles = (E + TILE - 1) >> TILE_SHIFT;

  size_t o = 0;
  auto carve = [&](size_t bytes) -> void* {
    void* p = (char*)d_ws + o;
    o += (bytes + 255) & ~(size_t)255;
    return p;
  };
  __half* X = (__half*)carve((size_t)N * 64 * 2);
  size_t hbytes = (size_t)N * 64 * 2;  // fp16 H'
  size_t rbytes = (size_t)E * 8;
  __half* H = (__half*)carve(hbytes > rbytes ? hbytes : rbytes);  // raw overlays H
  int2* raw = (int2*)H;
  unsigned char* Hq = (unsigned char*)carve((size_t)N * 64);  // e5m2 H'
  unsigned int* edat = (unsigned int*)carve((size_t)E * 4);   // {r:20, q12:12}
  float* Sx = (float*)carve((size_t)N * 6 * 4);
  float* vfs = (float*)carve((size_t)N * 6 * 4);
  float* dinv = (float*)carve((size_t)N * 4);
  int* boff = (int*)carve((size_t)(M + 1) * 4);
  int* bnextp = (int*)carve((size_t)M * 16 * 4);  // line-padded cursors
  int* gcnt = (int*)carve((size_t)M * 4);
  int* gtile = (int*)carve((size_t)tiles * NB * 4);
  int* offn = (int*)carve((size_t)(N + 1) * 4);
  float* h5 = (float*)carve((size_t)N * 4);
  const int nb5 = (N + 255) / 256;
  float* partials = (float*)carve((size_t)nb5 * 4);

  hipMemsetAsync(gcnt, 0, (size_t)M * 4, stream);

  k_count<<<tiles, 256, 0, stream>>>(col, gcnt, gtile, E, NB);
  k_bscan<<<1, 1024, 0, stream>>>(gcnt, boff, bnextp, offn, M, N);
  k_tscatter<<<tiles, 256, 0, stream>>>(row, col, w, gtile, bnextp, raw, E, NB);
  k_bsort<<<NB, 256, 0, stream>>>(raw, boff, vf, edat, offn, dinv, vfs, N);

  // layer 1: aggregate (D=6) on scaled features, dense 6->64 (fp16 X out)
  k_agg6<<<(N + 31) / 32, 256, 0, stream>>>(vfs, dinv, offn, edat, Sx, N);
  k_gemm1<<<(N + 63) / 64, 256, 0, stream>>>(Sx, W1, b1, X, N);

  // layers 2-4: gemm64 (fp16 H') -> pack (e5m2) -> agg64 (fp8 gather)
  const int nbA = (N + 15) / 16;
  const int total8 = N * 8;  // N*64/8 vec-units
  const int pb = (total8 + 255) / 256;
  k_gemm64<<<(N + 63) / 64, 256, 0, stream>>>(X, W2, dinv, H, N);
  k_pack<<<pb, 256, 0, stream>>>(H, Hq, total8);
  k_agg64<false><<<nbA, 256, 0, stream>>>(Hq, dinv, offn, edat, b2, W5, X, h5, N);
  k_gemm64<<<(N + 63) / 64, 256, 0, stream>>>(X, W3, dinv, H, N);
  k_pack<<<pb, 256, 0, stream>>>(H, Hq, total8);
  k_agg64<false><<<nbA, 256, 0, stream>>>(Hq, dinv, offn, edat, b3, W5, X, h5, N);
  k_gemm64<<<(N + 63) / 64, 256, 0, stream>>>(X, W4, dinv, H, N);
  k_pack<<<pb, 256, 0, stream>>>(H, Hq, total8);
  k_agg64<true><<<nbA, 256, 0, stream>>>(Hq, dinv, offn, edat, b4, W5, X, h5, N);

  // layer 5: scalar aggregation + mean
  k_agg5<<<nb5, 256, 0, stream>>>(h5, dinv, offn, edat, b5, partials, N);
  k_final<<<1, 512, 0, stream>>>(partials, out, nb5, 1.0f / (float)N);
}

// Round 20
// 393.096 us; speedup vs baseline: 1.3310x; 1.2190x over previous
//
#include <hip/hip_runtime.h>
#include <hip/hip_fp16.h>
#include <math.h>

// GCN 5-layer on MI355X — round 20: occupancy fixes.
//  (a) gemm64: __launch_bounds__(256,2) + unroll-16 k-loop. R19 profile showed
//      VGPR=256 / occ 8.7% / 410 GB/s — latency-bound from register pressure
//      (predates the fp8 codec; mis-attributed in R14/15).
//  (b) tscatter: bkt[] eliminated — bucket id packed into buf.y high 16 bits,
//      w truncated to fp16 (RN) in low 16. LDS 48->40KB, 3->4 blocks/CU.
// Rest as R19: quarter-wave v_perm agg64, 4B edges {r:20,q12:12}, fp16 X,
// fp16-H gemm64 + k_pack -> e5m2 Hq, merged bsort with vfs scaling.

__device__ __forceinline__ float sigf(float x) { return 1.0f / (1.0f + expf(-x)); }

// decode two e5m2 bytes (lo=feat0, hi=feat1) -> float2 (non-hot paths)
__device__ __forceinline__ float2 bf8x2_to_float2(unsigned short v) {
  unsigned int h2 = ((unsigned int)(v & 0xff00u) << 16) | ((unsigned int)(v & 0x00ffu) << 8);
  __half2 h = *reinterpret_cast<__half2*>(&h2);
  return __half22float2(h);
}

// decode 12-bit e5m7 (positive) -> float (non-hot paths)
__device__ __forceinline__ float q12f(unsigned int q) {
  unsigned short hb = (unsigned short)(q << 3);
  __half h = *reinterpret_cast<__half*>(&hb);
  return __half2float(h);
}

#define RMASK 0xFFFFF
#define SUBS 8            // cursor streams per bucket (blockIdx & 7)
#define TILE_SHIFT 12     // 4096 edges per tile
#define TILE (1 << TILE_SHIFT)
#define NBMAX 512

__global__ __launch_bounds__(256) void k_count(const int* __restrict__ col,
                                               int* __restrict__ gcnt,
                                               int* __restrict__ gtile, int E, int NB) {
  __shared__ int lc[NBMAX];
  int t = threadIdx.x;
  for (int i = t; i < NB; i += 256) lc[i] = 0;
  __syncthreads();
  int base = blockIdx.x << TILE_SHIFT;
  int sub = blockIdx.x & (SUBS - 1);
  int hi = base + TILE; if (hi > E) hi = E;
  for (int e = base + t; e < hi; e += 256) atomicAdd(&lc[col[e] >> 8], 1);
  __syncthreads();
  size_t gt = (size_t)blockIdx.x * NB;
  for (int i = t; i < NB; i += 256) {
    int c = lc[i];
    gtile[gt + i] = c;
    if (c) atomicAdd(&gcnt[i * SUBS + sub], c);
  }
}

// scan M = NB*SUBS counters; cursors line-padded (16 ints apart)
__global__ __launch_bounds__(1024) void k_bscan(const int* __restrict__ gcnt,
                                                int* __restrict__ boff,
                                                int* __restrict__ bnextp,
                                                int* __restrict__ offn, int M, int N) {
  __shared__ int s[1024];
  int t = threadIdx.x;
  int chunk = (M + 1023) / 1024;
  int lo = t * chunk; if (lo > M) lo = M;
  int hi = lo + chunk; if (hi > M) hi = M;
  int sum = 0;
  for (int i = lo; i < hi; ++i) sum += gcnt[i];
  s[t] = sum;
  __syncthreads();
  for (int d = 1; d < 1024; d <<= 1) {
    int v = (t >= d) ? s[t - d] : 0;
    __syncthreads();
    s[t] += v;
    __syncthreads();
  }
  int run = s[t] - sum;
  for (int i = lo; i < hi; ++i) {
    boff[i] = run;
    bnextp[(size_t)i * 16] = run;
    run += gcnt[i];
  }
  if (t == 1023) { boff[M] = s[1023]; offn[N] = s[1023]; }
}

// LDS-staged tile scatter: sort tile into LDS by bucket, then coalesced runs.
// buf.y = (bucket << 16) | fp16bits(w); bsort decodes w from low 16.
__global__ __launch_bounds__(256) void k_tscatter(const int* __restrict__ row,
                                                  const int* __restrict__ col,
                                                  const float* __restrict__ w,
                                                  const int* __restrict__ gtile,
                                                  int* __restrict__ bnextp,
                                                  int2* __restrict__ raw, int E, int NB) {
  __shared__ int2 buf[TILE];            // 32 KB
  __shared__ int loff[NBMAX];
  __shared__ int lc[NBMAX];
  __shared__ int shift[NBMAX];
  __shared__ int sc[256];
  int t = threadIdx.x;
  int e0 = blockIdx.x << TILE_SHIFT;
  int sub = blockIdx.x & (SUBS - 1);
  int e1 = e0 + TILE; if (e1 > E) e1 = E;
  size_t gt = (size_t)blockIdx.x * NB;
  // per-tile counts -> local offsets (512-entry scan with 256 threads)
  int c0 = (2 * t < NB) ? gtile[gt + 2 * t] : 0;
  int c1 = (2 * t + 1 < NB) ? gtile[gt + 2 * t + 1] : 0;
  sc[t] = c0 + c1;
  __syncthreads();
  for (int d = 1; d < 256; d <<= 1) {
    int v = (t >= d) ? sc[t - d] : 0;
    __syncthreads();
    sc[t] += v;
    __syncthreads();
  }
  int excl = sc[t] - (c0 + c1);
  if (2 * t < NB) { loff[2 * t] = excl; lc[2 * t] = 0; }
  if (2 * t + 1 < NB) { loff[2 * t + 1] = excl + c0; lc[2 * t + 1] = 0; }
  __syncthreads();
  // reserve global runs: one atomic per (tile,bucket)
  for (int i = t; i < NB; i += 256) {
    int cnt = gtile[gt + i];
    int gb = cnt ? atomicAdd(&bnextp[(size_t)(i * SUBS + sub) * 16], cnt) : 0;
    shift[i] = gb - loff[i];
  }
  __syncthreads();
  // pass 2: sort edges into LDS (bucket packed in y high bits)
  for (int e = e0 + t; e < e1; e += 256) {
    int c = col[e];
    int b = c >> 8;
    int pl = loff[b] + atomicAdd(&lc[b], 1);
    unsigned int wh = (unsigned int)__half_as_ushort(__float2half(w[e]));
    buf[pl] = make_int2(row[e] | ((c & 255) << 20), (int)((unsigned)b << 16 | wh));
  }
  __syncthreads();
  // pass 3: coalesced run writes
  int total = e1 - e0;
  for (int i = t; i < total; i += 256) {
    int2 v = buf[i];
    int b = ((unsigned)v.y) >> 16;
    raw[shift[b] + i] = v;
  }
}

// Merged per-bucket counting sort: offn/dinv + vfs scaling + scatter
// edat = u32 {r:20, q12(w*dinv[c]):12}.  w decoded from raw.y low 16 bits.
__global__ __launch_bounds__(256) void k_bsort(const int2* __restrict__ raw,
                                               const int* __restrict__ boff,
                                               const float* __restrict__ vf,
                                               unsigned int* __restrict__ edat,
                                               int* __restrict__ offn,
                                               float* __restrict__ dinv,
                                               float* __restrict__ vfs, int N) {
  __shared__ int cnt[256];
  __shared__ float wsum[256];
  __shared__ int s[256];
  __shared__ int pos[256];
  __shared__ float dl[256];
  int t = threadIdx.x, b = blockIdx.x;
  int e0 = boff[b * SUBS], e1 = boff[(b + 1) * SUBS];
  cnt[t] = 0;
  wsum[t] = 0.0f;
  __syncthreads();
  for (int e = e0 + t; e < e1; e += 256) {
    int2 a = raw[e];
    int cl = ((unsigned)a.x) >> 20;
    unsigned short wh = (unsigned short)(a.y & 0xffff);
    atomicAdd(&cnt[cl], 1);
    atomicAdd(&wsum[cl], __half2float(*reinterpret_cast<__half*>(&wh)));
  }
  __syncthreads();
  int c = cnt[t];
  s[t] = c;
  __syncthreads();
  for (int d = 1; d < 256; d <<= 1) {
    int v = (t >= d) ? s[t - d] : 0;
    __syncthreads();
    s[t] += v;
    __syncthreads();
  }
  int excl = s[t] - c;
  float dv = rsqrtf(wsum[t] + 1.0f);
  int node = b * 256 + t;
  if (node < N) {
    dinv[node] = dv;
    offn[node] = e0 + excl;
#pragma unroll
    for (int f = 0; f < 6; ++f) vfs[node * 6 + f] = dv * vf[node * 6 + f];
  }
  pos[t] = e0 + excl;
  dl[t] = dv;
  __syncthreads();
  for (int e = e0 + t; e < e1; e += 256) {
    int2 a = raw[e];
    int cl = ((unsigned)a.x) >> 20;
    unsigned short wh = (unsigned short)(a.y & 0xffff);
    float nrm = __half2float(*reinterpret_cast<__half*>(&wh)) * dl[cl];
    unsigned int q = ((unsigned int)__half_as_ushort(__float2half(nrm)) + 4u) >> 3;
    int p = atomicAdd(&pos[cl], 1);
    edat[p] = (unsigned int)(a.x & RMASK) | (q << 20);
  }
}

// Layer-1 aggregation on scaled features; 8 lanes/node; read-only.
__global__ __launch_bounds__(256) void k_agg6(const float* __restrict__ vfs,
                                              const float* __restrict__ dinv,
                                              const int* __restrict__ offn,
                                              const unsigned int* __restrict__ edat,
                                              float* __restrict__ Sx, int N) {
  int t = threadIdx.x, g = t >> 3, f = t & 7;
  int node = blockIdx.x * 32 + g;
  if (node >= N) return;
  bool act = f < 6;
  float dc = dinv[node];
  float acc = act ? dc * vfs[node * 6 + f] : 0.0f;  // dinv^2*vf = dinv*vfs
  int e1 = offn[node + 1];
  for (int e = offn[node]; e < e1; ++e) {
    unsigned int a = edat[e];
    if (act) acc += q12f(a >> 20) * vfs[(a & RMASK) * 6 + f];
  }
  if (act) Sx[node * 6 + f] = acc;
}

// X(half) = sigmoid(Sx @ W1 + b1), Sx [N,6], W1 [6,64]
__global__ __launch_bounds__(256) void k_gemm1(const float* __restrict__ Sx,
                                               const float* __restrict__ W1,
                                               const float* __restrict__ b1,
                                               __half* __restrict__ X, int N) {
  __shared__ float Wl[6 * 64];
  __shared__ float bl[64];
  __shared__ float XT[6 * 65];
  int t = threadIdx.x;
  int n0 = blockIdx.x * 64;
  for (int i = t; i < 384; i += 256) {
    Wl[i] = W1[i];
    int n = i / 6, k = i - n * 6;
    int node = n0 + n;
    XT[k * 65 + n] = (node < N) ? Sx[node * 6 + k] : 0.0f;
  }
  if (t < 64) bl[t] = b1[t];
  __syncthreads();
  int c0 = (t & 15) * 4;
  int nn = (t >> 4) * 4;
  float acc[4][4];
#pragma unroll
  for (int i = 0; i < 4; ++i)
#pragma unroll
    for (int j = 0; j < 4; ++j) acc[i][j] = bl[c0 + j];
#pragma unroll
  for (int k = 0; k < 6; ++k) {
    float4 wv = *(const float4*)&Wl[k * 64 + c0];
    float xv[4];
#pragma unroll
    for (int i = 0; i < 4; ++i) xv[i] = XT[k * 65 + nn + i];
#pragma unroll
    for (int i = 0; i < 4; ++i) {
      acc[i][0] += xv[i] * wv.x;
      acc[i][1] += xv[i] * wv.y;
      acc[i][2] += xv[i] * wv.z;
      acc[i][3] += xv[i] * wv.w;
    }
  }
#pragma unroll
  for (int i = 0; i < 4; ++i) {
    int node = n0 + nn + i;
    if (node < N) {
      __half2* dst = (__half2*)(X + (size_t)node * 64 + c0);
      dst[0] = __floats2half2_rn(sigf(acc[i][0]), sigf(acc[i][1]));
      dst[1] = __floats2half2_rn(sigf(acc[i][2]), sigf(acc[i][3]));
    }
  }
}

// H'(half) = dinv .* (X(half) @ W(f32)). 64x64 tile per block.
// launch_bounds(256,2) caps VGPR at 128 (R19: VGPR 256 -> occ 8.7%).
__global__ __launch_bounds__(256, 2) void k_gemm64(const __half* __restrict__ Xin,
                                                   const float* __restrict__ W,
                                                   const float* __restrict__ dinv,
                                                   __half* __restrict__ Hout, int N) {
  __shared__ float XT[64 * 65];
  __shared__ float Wl[64 * 64];
  int t = threadIdx.x;
  int n0 = blockIdx.x * 64;
#pragma unroll
  for (int i = 0; i < 4; ++i) {
    int idx = (i * 256 + t) * 4;
    *(float4*)&Wl[idx] = *(const float4*)&W[idx];
  }
#pragma unroll
  for (int i = 0; i < 2; ++i) {
    int idx = (i * 256 + t) * 8;
    int n = idx >> 6, k = idx & 63;
    int node = n0 + n;
    __half2 hv[4];
    if (node < N) {
      const __half2* src = (const __half2*)(Xin + (size_t)node * 64 + k);
      hv[0] = src[0]; hv[1] = src[1]; hv[2] = src[2]; hv[3] = src[3];
    } else {
      hv[0] = hv[1] = hv[2] = hv[3] = __floats2half2_rn(0.f, 0.f);
    }
#pragma unroll
    for (int j = 0; j < 4; ++j) {
      float2 f = __half22float2(hv[j]);
      XT[(k + 2 * j) * 65 + n] = f.x;
      XT[(k + 2 * j + 1) * 65 + n] = f.y;
    }
  }
  __syncthreads();
  int c0 = (t & 15) * 4;
  int nn = (t >> 4) * 4;
  float acc[4][4] = {{0.f}};
#pragma unroll 16
  for (int k = 0; k < 64; ++k) {
    float4 wv = *(const float4*)&Wl[k * 64 + c0];
    float xv[4];
#pragma unroll
    for (int i = 0; i < 4; ++i) xv[i] = XT[k * 65 + nn + i];
#pragma unroll
    for (int i = 0; i < 4; ++i) {
      acc[i][0] += xv[i] * wv.x;
      acc[i][1] += xv[i] * wv.y;
      acc[i][2] += xv[i] * wv.z;
      acc[i][3] += xv[i] * wv.w;
    }
  }
#pragma unroll
  for (int i = 0; i < 4; ++i) {
    int node = n0 + nn + i;
    if (node < N) {
      float dv = dinv[node];
      __half2* dst = (__half2*)(Hout + (size_t)node * 64 + c0);
      dst[0] = __floats2half2_rn(dv * acc[i][0], dv * acc[i][1]);
      dst[1] = __floats2half2_rn(dv * acc[i][2], dv * acc[i][3]);
    }
  }
}

// Streaming truncate: fp16 H' -> e5m2 Hq. 8 halves -> 8 bytes per thread.
__global__ __launch_bounds__(256) void k_pack(const __half* __restrict__ H,
                                              unsigned char* __restrict__ Hq,
                                              int total8) {
  int i = blockIdx.x * 256 + threadIdx.x;
  if (i >= total8) return;
  uint4 v = ((const uint4*)H)[i];  // 8 halves
  unsigned int lo, hi;
  {
    unsigned int a = ((v.x & 0xffffu) + 0x80u) >> 8;
    unsigned int b = (((v.x >> 16) & 0xffffu) + 0x80u) >> 8;
    unsigned int c = ((v.y & 0xffffu) + 0x80u) >> 8;
    unsigned int d = (((v.y >> 16) & 0xffffu) + 0x80u) >> 8;
    lo = (a & 0xffu) | ((b & 0xffu) << 8) | ((c & 0xffu) << 16) | ((d & 0xffu) << 24);
  }
  {
    unsigned int a = ((v.z & 0xffffu) + 0x80u) >> 8;
    unsigned int b = (((v.z >> 16) & 0xffffu) + 0x80u) >> 8;
    unsigned int c = ((v.w & 0xffffu) + 0x80u) >> 8;
    unsigned int d = (((v.w >> 16) & 0xffffu) + 0x80u) >> 8;
    hi = (a & 0xffu) | ((b & 0xffu) << 8) | ((c & 0xffu) << 16) | ((d & 0xffu) << 24);
  }
  ((uint2*)Hq)[i] = make_uint2(lo, hi);
}

// Quarter-wave-per-node CSC gather agg on e5m2 H'; lane owns feats {4l..4l+3}.
// v_perm expands 4 e5m2 bytes -> 2 half2; 2 pk_fma per edge.
// LAST: h5' = dinv * (x . W5).
template <bool LAST>
__global__ __launch_bounds__(256) void k_agg64(const unsigned char* __restrict__ Hq,
                                               const float* __restrict__ dinv,
                                               const int* __restrict__ offn,
                                               const unsigned int* __restrict__ edat,
                                               const float* __restrict__ b,
                                               const float* __restrict__ W5,
                                               __half* __restrict__ Xout,
                                               float* __restrict__ h5, int N) {
  const unsigned int* Hu = (const unsigned int*)Hq;  // [N][16] e5m2x4
  const unsigned int sel0 = 0x01040004u;  // {0, b0, 0, b1} from lo operand
  const unsigned int sel1 = 0x03040204u;  // {0, b2, 0, b3}
  int t = threadIdx.x;
  int l = t & 15;
  int qw = t >> 4;  // 16 quarter-waves per block
  int node = blockIdx.x * 16 + qw;
  if (node >= N) return;
  float di = dinv[node];
  unsigned int sh = Hu[(unsigned int)node * 16 + l];
  unsigned int sb0 = __builtin_amdgcn_perm(0u, sh, sel0);
  unsigned int sb1 = __builtin_amdgcn_perm(0u, sh, sel1);
  float2 f01 = __half22float2(*reinterpret_cast<__half2*>(&sb0));
  float2 f23 = __half22float2(*reinterpret_cast<__half2*>(&sb1));
  __half2 acc0 = __floats2half2_rn(di * f01.x, di * f01.y);
  __half2 acc1 = __floats2half2_rn(di * f23.x, di * f23.y);
  int e = offn[node], e1 = offn[node + 1];
  for (; e + 7 < e1; e += 8) {
    unsigned int a[8];
    unsigned int hv[8];
#pragma unroll
    for (int j = 0; j < 8; ++j) a[j] = edat[e + j];
#pragma unroll
    for (int j = 0; j < 8; ++j) hv[j] = Hu[(a[j] & RMASK) * 16u + l];
#pragma unroll
    for (int j = 0; j < 8; ++j) {
      unsigned int nmb = ((a[j] >> 20) << 3) * 0x10001u;  // {nm,nm} half bits
      unsigned int hb0 = __builtin_amdgcn_perm(0u, hv[j], sel0);
      unsigned int hb1 = __builtin_amdgcn_perm(0u, hv[j], sel1);
      acc0 = __hfma2(*reinterpret_cast<__half2*>(&nmb),
                     *reinterpret_cast<__half2*>(&hb0), acc0);
      acc1 = __hfma2(*reinterpret_cast<__half2*>(&nmb),
                     *reinterpret_cast<__half2*>(&hb1), acc1);
    }
  }
  for (; e < e1; ++e) {
    unsigned int a = edat[e];
    unsigned int hv = Hu[(a & RMASK) * 16u + l];
    unsigned int nmb = ((a >> 20) << 3) * 0x10001u;
    unsigned int hb0 = __builtin_amdgcn_perm(0u, hv, sel0);
    unsigned int hb1 = __builtin_amdgcn_perm(0u, hv, sel1);
    acc0 = __hfma2(*reinterpret_cast<__half2*>(&nmb),
                   *reinterpret_cast<__half2*>(&hb0), acc0);
    acc1 = __hfma2(*reinterpret_cast<__half2*>(&nmb),
                   *reinterpret_cast<__half2*>(&hb1), acc1);
  }
  float2 a01 = __half22float2(acc0);
  float2 a23 = __half22float2(acc1);
  float4 bb = ((const float4*)b)[l];
  float x0 = sigf(a01.x + bb.x);
  float x1 = sigf(a01.y + bb.y);
  float x2 = sigf(a23.x + bb.z);
  float x3 = sigf(a23.y + bb.w);
  if (LAST) {
    float4 w5 = ((const float4*)W5)[l];
    float v = x0 * w5.x + x1 * w5.y + x2 * w5.z + x3 * w5.w;
#pragma unroll
    for (int d = 8; d; d >>= 1) v += __shfl_xor(v, d);  // within quarter-wave
    if (l == 0) h5[node] = di * v;  // h5' = dinv * (x . W5)
  } else {
    __half2 o0 = __floats2half2_rn(x0, x1);
    __half2 o1 = __floats2half2_rn(x2, x3);
    ((uint2*)(Xout + (size_t)node * 64))[l] =
        make_uint2(*reinterpret_cast<unsigned int*>(&o0),
                   *reinterpret_cast<unsigned int*>(&o1));
  }
}

// scalar CSC aggregation on h5' + sigmoid + per-block partial sum
__global__ __launch_bounds__(256) void k_agg5(const float* __restrict__ h5,
                                              const float* __restrict__ dinv,
                                              const int* __restrict__ offn,
                                              const unsigned int* __restrict__ edat,
                                              const float* __restrict__ b5,
                                              float* __restrict__ partials, int N) {
  int n = blockIdx.x * 256 + threadIdx.x;
  float sig = 0.0f;
  if (n < N) {
    float di = dinv[n];
    float acc = di * h5[n];  // dinv^2 * (x.W5) = dinv * h5'
    int e1 = offn[n + 1];
    for (int e = offn[n]; e < e1; ++e) {
      unsigned int a = edat[e];
      acc += q12f(a >> 20) * h5[a & RMASK];
    }
    sig = sigf(acc + b5[0]);
  }
#pragma unroll
  for (int d = 32; d; d >>= 1) sig += __shfl_xor(sig, d);
  __shared__ float ws[4];
  int lane = threadIdx.x & 63, wid = threadIdx.x >> 6;
  if (lane == 0) ws[wid] = sig;
  __syncthreads();
  if (threadIdx.x == 0) partials[blockIdx.x] = ws[0] + ws[1] + ws[2] + ws[3];
}

__global__ __launch_bounds__(512) void k_final(const float* __restrict__ partials,
                                               float* __restrict__ out, int nb,
                                               float invN) {
  float v = 0.0f;
  for (int i = threadIdx.x; i < nb; i += 512) v += partials[i];
#pragma unroll
  for (int d = 32; d; d >>= 1) v += __shfl_xor(v, d);
  __shared__ float ws[8];
  int lane = threadIdx.x & 63, wid = threadIdx.x >> 6;
  if (lane == 0) ws[wid] = v;
  __syncthreads();
  if (threadIdx.x == 0) {
    float s = 0.0f;
    for (int i = 0; i < 8; ++i) s += ws[i];
    out[0] = s * invN;
  }
}

extern "C" void kernel_launch(void* const* d_in, const int* in_sizes, int n_in,
                              void* d_out, int out_size, void* d_ws, size_t ws_size,
                              hipStream_t stream) {
  const float* vf = (const float*)d_in[0];
  const int* edges = (const int*)d_in[1];
  const float* w = (const float*)d_in[2];
  const float* W1 = (const float*)d_in[3];
  const float* b1 = (const float*)d_in[4];
  const float* W2 = (const float*)d_in[5];
  const float* b2 = (const float*)d_in[6];
  const float* W3 = (const float*)d_in[7];
  const float* b3 = (const float*)d_in[8];
  const float* W4 = (const float*)d_in[9];
  const float* b4 = (const float*)d_in[10];
  const float* W5 = (const float*)d_in[11];
  const float* b5 = (const float*)d_in[12];
  float* out = (float*)d_out;

  const int N = in_sizes[0] / 6;
  const int E = in_sizes[2];
  const int* row = edges;
  const int* col = edges + E;
  const int NB = (N + 255) >> 8;
  const int M = NB * SUBS;
  const int tiles = (E + TILE - 1) >> TILE_SHIFT;

  size_t o = 0;
  auto carve = [&](size_t bytes) -> void* {
    void* p = (char*)d_ws + o;
    o += (bytes + 255) & ~(size_t)255;
    return p;
  };
  __half* X = (__half*)carve((size_t)N * 64 * 2);
  size_t hbytes = (size_t)N * 64 * 2;  // fp16 H'
  size_t rbytes = (size_t)E * 8;
  __half* H = (__half*)carve(hbytes > rbytes ? hbytes : rbytes);  // raw overlays H
  int2* raw = (int2*)H;
  unsigned char* Hq = (unsigned char*)carve((size_t)N * 64);  // e5m2 H'
  unsigned int* edat = (unsigned int*)carve((size_t)E * 4);   // {r:20, q12:12}
  float* Sx = (float*)carve((size_t)N * 6 * 4);
  float* vfs = (float*)carve((size_t)N * 6 * 4);
  float* dinv = (float*)carve((size_t)N * 4);
  int* boff = (int*)carve((size_t)(M + 1) * 4);
  int* bnextp = (int*)carve((size_t)M * 16 * 4);  // line-padded cursors
  int* gcnt = (int*)carve((size_t)M * 4);
  int* gtile = (int*)carve((size_t)tiles * NB * 4);
  int* offn = (int*)carve((size_t)(N + 1) * 4);
  float* h5 = (float*)carve((size_t)N * 4);
  const int nb5 = (N + 255) / 256;
  float* partials = (float*)carve((size_t)nb5 * 4);

  hipMemsetAsync(gcnt, 0, (size_t)M * 4, stream);

  k_count<<<tiles, 256, 0, stream>>>(col, gcnt, gtile, E, NB);
  k_bscan<<<1, 1024, 0, stream>>>(gcnt, boff, bnextp, offn, M, N);
  k_tscatter<<<tiles, 256, 0, stream>>>(row, col, w, gtile, bnextp, raw, E, NB);
  k_bsort<<<NB, 256, 0, stream>>>(raw, boff, vf, edat, offn, dinv, vfs, N);

  // layer 1: aggregate (D=6) on scaled features, dense 6->64 (fp16 X out)
  k_agg6<<<(N + 31) / 32, 256, 0, stream>>>(vfs, dinv, offn, edat, Sx, N);
  k_gemm1<<<(N + 63) / 64, 256, 0, stream>>>(Sx, W1, b1, X, N);

  // layers 2-4: gemm64 (fp16 H') -> pack (e5m2) -> agg64 (fp8 gather)
  const int nbA = (N + 15) / 16;
  const int total8 = N * 8;  // N*64/8 vec-units
  const int pb = (total8 + 255) / 256;
  k_gemm64<<<(N + 63) / 64, 256, 0, stream>>>(X, W2, dinv, H, N);
  k_pack<<<pb, 256, 0, stream>>>(H, Hq, total8);
  k_agg64<false><<<nbA, 256, 0, stream>>>(Hq, dinv, offn, edat, b2, W5, X, h5, N);
  k_gemm64<<<(N + 63) / 64, 256, 0, stream>>>(X, W3, dinv, H, N);
  k_pack<<<pb, 256, 0, stream>>>(H, Hq, total8);
  k_agg64<false><<<nbA, 256, 0, stream>>>(Hq, dinv, offn, edat, b3, W5, X, h5, N);
  k_gemm64<<<(N + 63) / 64, 256, 0, stream>>>(X, W4, dinv, H, N);
  k_pack<<<pb, 256, 0, stream>>>(H, Hq, total8);
  k_agg64<true><<<nbA, 256, 0, stream>>>(Hq, dinv, offn, edat, b4, W5, X, h5, N);

  // layer 5: scalar aggregation + mean
  k_agg5<<<nb5, 256, 0, stream>>>(h5, dinv, offn, edat, b5, partials, N);
  k_final<<<1, 512, 0, stream>>>(partials, out, nb5, 1.0f / (float)N);
}

// Round 22
// 382.864 us; speedup vs baseline: 1.3665x; 1.0267x over previous
//
#include <hip/hip_runtime.h>
#include <hip/hip_fp16.h>
#include <math.h>

// GCN 5-layer on MI355X — round 21 (resubmit after infra failure):
//  (a) k_bsort at 512 threads (R20: 391 blocks x 4 waves = grid-starved,
//      occ 12%, 879 GB/s). Edge loops stride 512; scan on first 256.
//  (b) e5m2 pack fused into gemm64 epilogue (R15's "amplification" was
//      VGPR-256 spill, now capped by launch_bounds(256,2)): half2 + 0x800080
//      round, one v_perm picks top bytes, one 4B coalesced store. k_pack and
//      the fp16 H buffer are gone.
// Rest as R20: quarter-wave v_perm agg64, 4B edges {r:20,q12:12}, fp16 X,
// LDS tile scatter with packed bucket ids, merged bsort with vfs scaling.

__device__ __forceinline__ float sigf(float x) { return 1.0f / (1.0f + expf(-x)); }

// decode 12-bit e5m7 (positive) -> float (non-hot paths)
__device__ __forceinline__ float q12f(unsigned int q) {
  unsigned short hb = (unsigned short)(q << 3);
  __half h = *reinterpret_cast<__half*>(&hb);
  return __half2float(h);
}

#define RMASK 0xFFFFF
#define SUBS 8            // cursor streams per bucket (blockIdx & 7)
#define TILE_SHIFT 12     // 4096 edges per tile
#define TILE (1 << TILE_SHIFT)
#define NBMAX 512

__global__ __launch_bounds__(256) void k_count(const int* __restrict__ col,
                                               int* __restrict__ gcnt,
                                               int* __restrict__ gtile, int E, int NB) {
  __shared__ int lc[NBMAX];
  int t = threadIdx.x;
  for (int i = t; i < NB; i += 256) lc[i] = 0;
  __syncthreads();
  int base = blockIdx.x << TILE_SHIFT;
  int sub = blockIdx.x & (SUBS - 1);
  int hi = base + TILE; if (hi > E) hi = E;
  for (int e = base + t; e < hi; e += 256) atomicAdd(&lc[col[e] >> 8], 1);
  __syncthreads();
  size_t gt = (size_t)blockIdx.x * NB;
  for (int i = t; i < NB; i += 256) {
    int c = lc[i];
    gtile[gt + i] = c;
    if (c) atomicAdd(&gcnt[i * SUBS + sub], c);
  }
}

// scan M = NB*SUBS counters; cursors line-padded (16 ints apart)
__global__ __launch_bounds__(1024) void k_bscan(const int* __restrict__ gcnt,
                                                int* __restrict__ boff,
                                                int* __restrict__ bnextp,
                                                int* __restrict__ offn, int M, int N) {
  __shared__ int s[1024];
  int t = threadIdx.x;
  int chunk = (M + 1023) / 1024;
  int lo = t * chunk; if (lo > M) lo = M;
  int hi = lo + chunk; if (hi > M) hi = M;
  int sum = 0;
  for (int i = lo; i < hi; ++i) sum += gcnt[i];
  s[t] = sum;
  __syncthreads();
  for (int d = 1; d < 1024; d <<= 1) {
    int v = (t >= d) ? s[t - d] : 0;
    __syncthreads();
    s[t] += v;
    __syncthreads();
  }
  int run = s[t] - sum;
  for (int i = lo; i < hi; ++i) {
    boff[i] = run;
    bnextp[(size_t)i * 16] = run;
    run += gcnt[i];
  }
  if (t == 1023) { boff[M] = s[1023]; offn[N] = s[1023]; }
}

// LDS-staged tile scatter: sort tile into LDS by bucket, then coalesced runs.
// buf.y = (bucket << 16) | fp16bits(w); bsort decodes w from low 16.
__global__ __launch_bounds__(256) void k_tscatter(const int* __restrict__ row,
                                                  const int* __restrict__ col,
                                                  const float* __restrict__ w,
                                                  const int* __restrict__ gtile,
                                                  int* __restrict__ bnextp,
                                                  int2* __restrict__ raw, int E, int NB) {
  __shared__ int2 buf[TILE];            // 32 KB
  __shared__ int loff[NBMAX];
  __shared__ int lc[NBMAX];
  __shared__ int shift[NBMAX];
  __shared__ int sc[256];
  int t = threadIdx.x;
  int e0 = blockIdx.x << TILE_SHIFT;
  int sub = blockIdx.x & (SUBS - 1);
  int e1 = e0 + TILE; if (e1 > E) e1 = E;
  size_t gt = (size_t)blockIdx.x * NB;
  int c0 = (2 * t < NB) ? gtile[gt + 2 * t] : 0;
  int c1 = (2 * t + 1 < NB) ? gtile[gt + 2 * t + 1] : 0;
  sc[t] = c0 + c1;
  __syncthreads();
  for (int d = 1; d < 256; d <<= 1) {
    int v = (t >= d) ? sc[t - d] : 0;
    __syncthreads();
    sc[t] += v;
    __syncthreads();
  }
  int excl = sc[t] - (c0 + c1);
  if (2 * t < NB) { loff[2 * t] = excl; lc[2 * t] = 0; }
  if (2 * t + 1 < NB) { loff[2 * t + 1] = excl + c0; lc[2 * t + 1] = 0; }
  __syncthreads();
  for (int i = t; i < NB; i += 256) {
    int cnt = gtile[gt + i];
    int gb = cnt ? atomicAdd(&bnextp[(size_t)(i * SUBS + sub) * 16], cnt) : 0;
    shift[i] = gb - loff[i];
  }
  __syncthreads();
  for (int e = e0 + t; e < e1; e += 256) {
    int c = col[e];
    int b = c >> 8;
    int pl = loff[b] + atomicAdd(&lc[b], 1);
    unsigned int wh = (unsigned int)__half_as_ushort(__float2half(w[e]));
    buf[pl] = make_int2(row[e] | ((c & 255) << 20), (int)((unsigned)b << 16 | wh));
  }
  __syncthreads();
  int total = e1 - e0;
  for (int i = t; i < total; i += 256) {
    int2 v = buf[i];
    int b = ((unsigned)v.y) >> 16;
    raw[shift[b] + i] = v;
  }
}

// Merged per-bucket counting sort (512 threads): offn/dinv + vfs scaling +
// scatter edat = u32 {r:20, q12(w*dinv[c]):12}. w decoded from raw.y low 16.
__global__ __launch_bounds__(512) void k_bsort(const int2* __restrict__ raw,
                                               const int* __restrict__ boff,
                                               const float* __restrict__ vf,
                                               unsigned int* __restrict__ edat,
                                               int* __restrict__ offn,
                                               float* __restrict__ dinv,
                                               float* __restrict__ vfs, int N) {
  __shared__ int cnt[256];
  __shared__ float wsum[256];
  __shared__ int s[256];
  __shared__ int pos[256];
  __shared__ float dl[256];
  int t = threadIdx.x, b = blockIdx.x;
  int e0 = boff[b * SUBS], e1 = boff[(b + 1) * SUBS];
  if (t < 256) { cnt[t] = 0; wsum[t] = 0.0f; }
  __syncthreads();
  for (int e = e0 + t; e < e1; e += 512) {
    int2 a = raw[e];
    int cl = ((unsigned)a.x) >> 20;
    unsigned short wh = (unsigned short)(a.y & 0xffff);
    atomicAdd(&cnt[cl], 1);
    atomicAdd(&wsum[cl], __half2float(*reinterpret_cast<__half*>(&wh)));
  }
  __syncthreads();
  int c = 0;
  if (t < 256) { c = cnt[t]; s[t] = c; }
  __syncthreads();
  for (int d = 1; d < 256; d <<= 1) {
    int v = (t < 256 && t >= d) ? s[t - d] : 0;
    __syncthreads();
    if (t < 256) s[t] += v;
    __syncthreads();
  }
  if (t < 256) {
    int excl = s[t] - c;
    float dv = rsqrtf(wsum[t] + 1.0f);
    int node = b * 256 + t;
    if (node < N) {
      dinv[node] = dv;
      offn[node] = e0 + excl;
#pragma unroll
      for (int f = 0; f < 6; ++f) vfs[node * 6 + f] = dv * vf[node * 6 + f];
    }
    pos[t] = e0 + excl;
    dl[t] = dv;
  }
  __syncthreads();
  for (int e = e0 + t; e < e1; e += 512) {
    int2 a = raw[e];
    int cl = ((unsigned)a.x) >> 20;
    unsigned short wh = (unsigned short)(a.y & 0xffff);
    float nrm = __half2float(*reinterpret_cast<__half*>(&wh)) * dl[cl];
    unsigned int q = ((unsigned int)__half_as_ushort(__float2half(nrm)) + 4u) >> 3;
    int p = atomicAdd(&pos[cl], 1);
    edat[p] = (unsigned int)(a.x & RMASK) | (q << 20);
  }
}

// Layer-1 aggregation on scaled features; 8 lanes/node; read-only.
__global__ __launch_bounds__(256) void k_agg6(const float* __restrict__ vfs,
                                              const float* __restrict__ dinv,
                                              const int* __restrict__ offn,
                                              const unsigned int* __restrict__ edat,
                                              float* __restrict__ Sx, int N) {
  int t = threadIdx.x, g = t >> 3, f = t & 7;
  int node = blockIdx.x * 32 + g;
  if (node >= N) return;
  bool act = f < 6;
  float dc = dinv[node];
  float acc = act ? dc * vfs[node * 6 + f] : 0.0f;  // dinv^2*vf = dinv*vfs
  int e1 = offn[node + 1];
  for (int e = offn[node]; e < e1; ++e) {
    unsigned int a = edat[e];
    if (act) acc += q12f(a >> 20) * vfs[(a & RMASK) * 6 + f];
  }
  if (act) Sx[node * 6 + f] = acc;
}

// X(half) = sigmoid(Sx @ W1 + b1), Sx [N,6], W1 [6,64]
__global__ __launch_bounds__(256) void k_gemm1(const float* __restrict__ Sx,
                                               const float* __restrict__ W1,
                                               const float* __restrict__ b1,
                                               __half* __restrict__ X, int N) {
  __shared__ float Wl[6 * 64];
  __shared__ float bl[64];
  __shared__ float XT[6 * 65];
  int t = threadIdx.x;
  int n0 = blockIdx.x * 64;
  for (int i = t; i < 384; i += 256) {
    Wl[i] = W1[i];
    int n = i / 6, k = i - n * 6;
    int node = n0 + n;
    XT[k * 65 + n] = (node < N) ? Sx[node * 6 + k] : 0.0f;
  }
  if (t < 64) bl[t] = b1[t];
  __syncthreads();
  int c0 = (t & 15) * 4;
  int nn = (t >> 4) * 4;
  float acc[4][4];
#pragma unroll
  for (int i = 0; i < 4; ++i)
#pragma unroll
    for (int j = 0; j < 4; ++j) acc[i][j] = bl[c0 + j];
#pragma unroll
  for (int k = 0; k < 6; ++k) {
    float4 wv = *(const float4*)&Wl[k * 64 + c0];
    float xv[4];
#pragma unroll
    for (int i = 0; i < 4; ++i) xv[i] = XT[k * 65 + nn + i];
#pragma unroll
    for (int i = 0; i < 4; ++i) {
      acc[i][0] += xv[i] * wv.x;
      acc[i][1] += xv[i] * wv.y;
      acc[i][2] += xv[i] * wv.z;
      acc[i][3] += xv[i] * wv.w;
    }
  }
#pragma unroll
  for (int i = 0; i < 4; ++i) {
    int node = n0 + nn + i;
    if (node < N) {
      __half2* dst = (__half2*)(X + (size_t)node * 64 + c0);
      dst[0] = __floats2half2_rn(sigf(acc[i][0]), sigf(acc[i][1]));
      dst[1] = __floats2half2_rn(sigf(acc[i][2]), sigf(acc[i][3]));
    }
  }
}

// Hq(e5m2) = dinv .* (X(half) @ W(f32)). Pack fused: half2 pair + 0x800080
// round, v_perm picks top bytes, one coalesced 4B store per thread per i.
__global__ __launch_bounds__(256, 2) void k_gemm64(const __half* __restrict__ Xin,
                                                   const float* __restrict__ W,
                                                   const float* __restrict__ dinv,
                                                   unsigned char* __restrict__ Hq, int N) {
  __shared__ float XT[64 * 65];
  __shared__ float Wl[64 * 64];
  int t = threadIdx.x;
  int n0 = blockIdx.x * 64;
#pragma unroll
  for (int i = 0; i < 4; ++i) {
    int idx = (i * 256 + t) * 4;
    *(float4*)&Wl[idx] = *(const float4*)&W[idx];
  }
#pragma unroll
  for (int i = 0; i < 2; ++i) {
    int idx = (i * 256 + t) * 8;
    int n = idx >> 6, k = idx & 63;
    int node = n0 + n;
    __half2 hv[4];
    if (node < N) {
      const __half2* src = (const __half2*)(Xin + (size_t)node * 64 + k);
      hv[0] = src[0]; hv[1] = src[1]; hv[2] = src[2]; hv[3] = src[3];
    } else {
      hv[0] = hv[1] = hv[2] = hv[3] = __floats2half2_rn(0.f, 0.f);
    }
#pragma unroll
    for (int j = 0; j < 4; ++j) {
      float2 f = __half22float2(hv[j]);
      XT[(k + 2 * j) * 65 + n] = f.x;
      XT[(k + 2 * j + 1) * 65 + n] = f.y;
    }
  }
  __syncthreads();
  int c0 = (t & 15) * 4;
  int nn = (t >> 4) * 4;
  float acc[4][4] = {{0.f}};
#pragma unroll 16
  for (int k = 0; k < 64; ++k) {
    float4 wv = *(const float4*)&Wl[k * 64 + c0];
    float xv[4];
#pragma unroll
    for (int i = 0; i < 4; ++i) xv[i] = XT[k * 65 + nn + i];
#pragma unroll
    for (int i = 0; i < 4; ++i) {
      acc[i][0] += xv[i] * wv.x;
      acc[i][1] += xv[i] * wv.y;
      acc[i][2] += xv[i] * wv.z;
      acc[i][3] += xv[i] * wv.w;
    }
  }
#pragma unroll
  for (int i = 0; i < 4; ++i) {
    int node = n0 + nn + i;
    if (node < N) {
      float dv = dinv[node];
      __half2 h01 = __floats2half2_rn(dv * acc[i][0], dv * acc[i][1]);
      __half2 h23 = __floats2half2_rn(dv * acc[i][2], dv * acc[i][3]);
      unsigned int r01 = *reinterpret_cast<unsigned int*>(&h01) + 0x00800080u;
      unsigned int r23 = *reinterpret_cast<unsigned int*>(&h23) + 0x00800080u;
      unsigned int packed = __builtin_amdgcn_perm(r23, r01, 0x07050301u);
      *(unsigned int*)(Hq + (size_t)node * 64 + c0) = packed;
    }
  }
}

// Quarter-wave-per-node CSC gather agg on e5m2 H'; lane owns feats {4l..4l+3}.
// v_perm expands 4 e5m2 bytes -> 2 half2; 2 pk_fma per edge.
// LAST: h5' = dinv * (x . W5).
template <bool LAST>
__global__ __launch_bounds__(256) void k_agg64(const unsigned char* __restrict__ Hq,
                                               const float* __restrict__ dinv,
                                               const int* __restrict__ offn,
                                               const unsigned int* __restrict__ edat,
                                               const float* __restrict__ b,
                                               const float* __restrict__ W5,
                                               __half* __restrict__ Xout,
                                               float* __restrict__ h5, int N) {
  const unsigned int* Hu = (const unsigned int*)Hq;  // [N][16] e5m2x4
  const unsigned int sel0 = 0x01040004u;  // {0, b0, 0, b1} from lo operand
  const unsigned int sel1 = 0x03040204u;  // {0, b2, 0, b3}
  int t = threadIdx.x;
  int l = t & 15;
  int qw = t >> 4;  // 16 quarter-waves per block
  int node = blockIdx.x * 16 + qw;
  if (node >= N) return;
  float di = dinv[node];
  unsigned int sh = Hu[(unsigned int)node * 16 + l];
  unsigned int sb0 = __builtin_amdgcn_perm(0u, sh, sel0);
  unsigned int sb1 = __builtin_amdgcn_perm(0u, sh, sel1);
  float2 f01 = __half22float2(*reinterpret_cast<__half2*>(&sb0));
  float2 f23 = __half22float2(*reinterpret_cast<__half2*>(&sb1));
  __half2 acc0 = __floats2half2_rn(di * f01.x, di * f01.y);
  __half2 acc1 = __floats2half2_rn(di * f23.x, di * f23.y);
  int e = offn[node], e1 = offn[node + 1];
  for (; e + 7 < e1; e += 8) {
    unsigned int a[8];
    unsigned int hv[8];
#pragma unroll
    for (int j = 0; j < 8; ++j) a[j] = edat[e + j];
#pragma unroll
    for (int j = 0; j < 8; ++j) hv[j] = Hu[(a[j] & RMASK) * 16u + l];
#pragma unroll
    for (int j = 0; j < 8; ++j) {
      unsigned int nmb = ((a[j] >> 20) << 3) * 0x10001u;  // {nm,nm} half bits
      unsigned int hb0 = __builtin_amdgcn_perm(0u, hv[j], sel0);
      unsigned int hb1 = __builtin_amdgcn_perm(0u, hv[j], sel1);
      acc0 = __hfma2(*reinterpret_cast<__half2*>(&nmb),
                     *reinterpret_cast<__half2*>(&hb0), acc0);
      acc1 = __hfma2(*reinterpret_cast<__half2*>(&nmb),
                     *reinterpret_cast<__half2*>(&hb1), acc1);
    }
  }
  for (; e < e1; ++e) {
    unsigned int a = edat[e];
    unsigned int hv = Hu[(a & RMASK) * 16u + l];
    unsigned int nmb = ((a >> 20) << 3) * 0x10001u;
    unsigned int hb0 = __builtin_amdgcn_perm(0u, hv, sel0);
    unsigned int hb1 = __builtin_amdgcn_perm(0u, hv, sel1);
    acc0 = __hfma2(*reinterpret_cast<__half2*>(&nmb),
                   *reinterpret_cast<__half2*>(&hb0), acc0);
    acc1 = __hfma2(*reinterpret_cast<__half2*>(&nmb),
                   *reinterpret_cast<__half2*>(&hb1), acc1);
  }
  float2 a01 = __half22float2(acc0);
  float2 a23 = __half22float2(acc1);
  float4 bb = ((const float4*)b)[l];
  float x0 = sigf(a01.x + bb.x);
  float x1 = sigf(a01.y + bb.y);
  float x2 = sigf(a23.x + bb.z);
  float x3 = sigf(a23.y + bb.w);
  if (LAST) {
    float4 w5 = ((const float4*)W5)[l];
    float v = x0 * w5.x + x1 * w5.y + x2 * w5.z + x3 * w5.w;
#pragma unroll
    for (int d = 8; d; d >>= 1) v += __shfl_xor(v, d);  // within quarter-wave
    if (l == 0) h5[node] = di * v;  // h5' = dinv * (x . W5)
  } else {
    __half2 o0 = __floats2half2_rn(x0, x1);
    __half2 o1 = __floats2half2_rn(x2, x3);
    ((uint2*)(Xout + (size_t)node * 64))[l] =
        make_uint2(*reinterpret_cast<unsigned int*>(&o0),
                   *reinterpret_cast<unsigned int*>(&o1));
  }
}

// scalar CSC aggregation on h5' + sigmoid + per-block partial sum
__global__ __launch_bounds__(256) void k_agg5(const float* __restrict__ h5,
                                              const float* __restrict__ dinv,
                                              const int* __restrict__ offn,
                                              const unsigned int* __restrict__ edat,
                                              const float* __restrict__ b5,
                                              float* __restrict__ partials, int N) {
  int n = blockIdx.x * 256 + threadIdx.x;
  float sig = 0.0f;
  if (n < N) {
    float di = dinv[n];
    float acc = di * h5[n];  // dinv^2 * (x.W5) = dinv * h5'
    int e1 = offn[n + 1];
    for (int e = offn[n]; e < e1; ++e) {
      unsigned int a = edat[e];
      acc += q12f(a >> 20) * h5[a & RMASK];
    }
    sig = sigf(acc + b5[0]);
  }
#pragma unroll
  for (int d = 32; d; d >>= 1) sig += __shfl_xor(sig, d);
  __shared__ float ws[4];
  int lane = threadIdx.x & 63, wid = threadIdx.x >> 6;
  if (lane == 0) ws[wid] = sig;
  __syncthreads();
  if (threadIdx.x == 0) partials[blockIdx.x] = ws[0] + ws[1] + ws[2] + ws[3];
}

__global__ __launch_bounds__(512) void k_final(const float* __restrict__ partials,
                                               float* __restrict__ out, int nb,
                                               float invN) {
  float v = 0.0f;
  for (int i = threadIdx.x; i < nb; i += 512) v += partials[i];
#pragma unroll
  for (int d = 32; d; d >>= 1) v += __shfl_xor(v, d);
  __shared__ float ws[8];
  int lane = threadIdx.x & 63, wid = threadIdx.x >> 6;
  if (lane == 0) ws[wid] = v;
  __syncthreads();
  if (threadIdx.x == 0) {
    float s = 0.0f;
    for (int i = 0; i < 8; ++i) s += ws[i];
    out[0] = s * invN;
  }
}

extern "C" void kernel_launch(void* const* d_in, const int* in_sizes, int n_in,
                              void* d_out, int out_size, void* d_ws, size_t ws_size,
                              hipStream_t stream) {
  const float* vf = (const float*)d_in[0];
  const int* edges = (const int*)d_in[1];
  const float* w = (const float*)d_in[2];
  const float* W1 = (const float*)d_in[3];
  const float* b1 = (const float*)d_in[4];
  const float* W2 = (const float*)d_in[5];
  const float* b2 = (const float*)d_in[6];
  const float* W3 = (const float*)d_in[7];
  const float* b3 = (const float*)d_in[8];
  const float* W4 = (const float*)d_in[9];
  const float* b4 = (const float*)d_in[10];
  const float* W5 = (const float*)d_in[11];
  const float* b5 = (const float*)d_in[12];
  float* out = (float*)d_out;

  const int N = in_sizes[0] / 6;
  const int E = in_sizes[2];
  const int* row = edges;
  const int* col = edges + E;
  const int NB = (N + 255) >> 8;
  const int M = NB * SUBS;
  const int tiles = (E + TILE - 1) >> TILE_SHIFT;

  size_t o = 0;
  auto carve = [&](size_t bytes) -> void* {
    void* p = (char*)d_ws + o;
    o += (bytes + 255) & ~(size_t)255;
    return p;
  };
  __half* X = (__half*)carve((size_t)N * 64 * 2);
  int2* raw = (int2*)carve((size_t)E * 8);
  unsigned char* Hq = (unsigned char*)carve((size_t)N * 64);  // e5m2 H'
  unsigned int* edat = (unsigned int*)carve((size_t)E * 4);   // {r:20, q12:12}
  float* Sx = (float*)carve((size_t)N * 6 * 4);
  float* vfs = (float*)carve((size_t)N * 6 * 4);
  float* dinv = (float*)carve((size_t)N * 4);
  int* boff = (int*)carve((size_t)(M + 1) * 4);
  int* bnextp = (int*)carve((size_t)M * 16 * 4);  // line-padded cursors
  int* gcnt = (int*)carve((size_t)M * 4);
  int* gtile = (int*)carve((size_t)tiles * NB * 4);
  int* offn = (int*)carve((size_t)(N + 1) * 4);
  float* h5 = (float*)carve((size_t)N * 4);
  const int nb5 = (N + 255) / 256;
  float* partials = (float*)carve((size_t)nb5 * 4);

  hipMemsetAsync(gcnt, 0, (size_t)M * 4, stream);

  k_count<<<tiles, 256, 0, stream>>>(col, gcnt, gtile, E, NB);
  k_bscan<<<1, 1024, 0, stream>>>(gcnt, boff, bnextp, offn, M, N);
  k_tscatter<<<tiles, 256, 0, stream>>>(row, col, w, gtile, bnextp, raw, E, NB);
  k_bsort<<<NB, 512, 0, stream>>>(raw, boff, vf, edat, offn, dinv, vfs, N);

  // layer 1: aggregate (D=6) on scaled features, dense 6->64 (fp16 X out)
  k_agg6<<<(N + 31) / 32, 256, 0, stream>>>(vfs, dinv, offn, edat, Sx, N);
  k_gemm1<<<(N + 63) / 64, 256, 0, stream>>>(Sx, W1, b1, X, N);

  // layers 2-4: gemm64 (fused e5m2 pack) -> agg64 (fp8 gather)
  const int nbA = (N + 15) / 16;
  k_gemm64<<<(N + 63) / 64, 256, 0, stream>>>(X, W2, dinv, Hq, N);
  k_agg64<false><<<nbA, 256, 0, stream>>>(Hq, dinv, offn, edat, b2, W5, X, h5, N);
  k_gemm64<<<(N + 63) / 64, 256, 0, stream>>>(X, W3, dinv, Hq, N);
  k_agg64<false><<<nbA, 256, 0, stream>>>(Hq, dinv, offn, edat, b3, W5, X, h5, N);
  k_gemm64<<<(N + 63) / 64, 256, 0, stream>>>(X, W4, dinv, Hq, N);
  k_agg64<true><<<nbA, 256, 0, stream>>>(Hq, dinv, offn, edat, b4, W5, X, h5, N);

  // layer 5: scalar aggregation + mean
  k_agg5<<<nb5, 256, 0, stream>>>(h5, dinv, offn, edat, b5, partials, N);
  k_final<<<1, 512, 0, stream>>>(partials, out, nb5, 1.0f / (float)N);
}

// Round 26
// 376.740 us; speedup vs baseline: 1.3887x; 1.0163x over previous
//
#include <hip/hip_runtime.h>
#include <hip/hip_fp16.h>
#include <math.h>

// GCN 5-layer on MI355X — round 23 kernel (resubmit x3 after infra failures):
//  (a) k_l1 = agg6+gemm1 fused: 8-lane group broadcasts its 6 Sx values via
//      shfl, every lane computes 8 sigmoid cols from LDS W1/b1, one uint4
//      fp16 store per lane. Sx buffer and one launch eliminated.
//  (b) gemm64 launch_bounds(256,3): LDS 32.6KB allows 4 blocks/CU; VGPR cap
//      ~170 (no spill expected) -> 3 blocks/CU vs 2.
// Rest as R22 (measured): quarter-wave v_perm agg64 (45us, ~15% over fabric
// floor), 4B edges {r:20,q12:12}, LDS tile scatter, 512-thread bsort,
// fused e5m2 pack in gemm64.

__device__ __forceinline__ float sigf(float x) { return 1.0f / (1.0f + expf(-x)); }

// decode 12-bit e5m7 (positive) -> float (non-hot paths)
__device__ __forceinline__ float q12f(unsigned int q) {
  unsigned short hb = (unsigned short)(q << 3);
  __half h = *reinterpret_cast<__half*>(&hb);
  return __half2float(h);
}

#define RMASK 0xFFFFF
#define SUBS 8            // cursor streams per bucket (blockIdx & 7)
#define TILE_SHIFT 12     // 4096 edges per tile
#define TILE (1 << TILE_SHIFT)
#define NBMAX 512

__global__ __launch_bounds__(256) void k_count(const int* __restrict__ col,
                                               int* __restrict__ gcnt,
                                               int* __restrict__ gtile, int E, int NB) {
  __shared__ int lc[NBMAX];
  int t = threadIdx.x;
  for (int i = t; i < NB; i += 256) lc[i] = 0;
  __syncthreads();
  int base = blockIdx.x << TILE_SHIFT;
  int sub = blockIdx.x & (SUBS - 1);
  int hi = base + TILE; if (hi > E) hi = E;
  for (int e = base + t; e < hi; e += 256) atomicAdd(&lc[col[e] >> 8], 1);
  __syncthreads();
  size_t gt = (size_t)blockIdx.x * NB;
  for (int i = t; i < NB; i += 256) {
    int c = lc[i];
    gtile[gt + i] = c;
    if (c) atomicAdd(&gcnt[i * SUBS + sub], c);
  }
}

// scan M = NB*SUBS counters; cursors line-padded (16 ints apart)
__global__ __launch_bounds__(1024) void k_bscan(const int* __restrict__ gcnt,
                                                int* __restrict__ boff,
                                                int* __restrict__ bnextp,
                                                int* __restrict__ offn, int M, int N) {
  __shared__ int s[1024];
  int t = threadIdx.x;
  int chunk = (M + 1023) / 1024;
  int lo = t * chunk; if (lo > M) lo = M;
  int hi = lo + chunk; if (hi > M) hi = M;
  int sum = 0;
  for (int i = lo; i < hi; ++i) sum += gcnt[i];
  s[t] = sum;
  __syncthreads();
  for (int d = 1; d < 1024; d <<= 1) {
    int v = (t >= d) ? s[t - d] : 0;
    __syncthreads();
    s[t] += v;
    __syncthreads();
  }
  int run = s[t] - sum;
  for (int i = lo; i < hi; ++i) {
    boff[i] = run;
    bnextp[(size_t)i * 16] = run;
    run += gcnt[i];
  }
  if (t == 1023) { boff[M] = s[1023]; offn[N] = s[1023]; }
}

// LDS-staged tile scatter: sort tile into LDS by bucket, then coalesced runs.
// buf.y = (bucket << 16) | fp16bits(w); bsort decodes w from low 16.
__global__ __launch_bounds__(256) void k_tscatter(const int* __restrict__ row,
                                                  const int* __restrict__ col,
                                                  const float* __restrict__ w,
                                                  const int* __restrict__ gtile,
                                                  int* __restrict__ bnextp,
                                                  int2* __restrict__ raw, int E, int NB) {
  __shared__ int2 buf[TILE];            // 32 KB
  __shared__ int loff[NBMAX];
  __shared__ int lc[NBMAX];
  __shared__ int shift[NBMAX];
  __shared__ int sc[256];
  int t = threadIdx.x;
  int e0 = blockIdx.x << TILE_SHIFT;
  int sub = blockIdx.x & (SUBS - 1);
  int e1 = e0 + TILE; if (e1 > E) e1 = E;
  size_t gt = (size_t)blockIdx.x * NB;
  int c0 = (2 * t < NB) ? gtile[gt + 2 * t] : 0;
  int c1 = (2 * t + 1 < NB) ? gtile[gt + 2 * t + 1] : 0;
  sc[t] = c0 + c1;
  __syncthreads();
  for (int d = 1; d < 256; d <<= 1) {
    int v = (t >= d) ? sc[t - d] : 0;
    __syncthreads();
    sc[t] += v;
    __syncthreads();
  }
  int excl = sc[t] - (c0 + c1);
  if (2 * t < NB) { loff[2 * t] = excl; lc[2 * t] = 0; }
  if (2 * t + 1 < NB) { loff[2 * t + 1] = excl + c0; lc[2 * t + 1] = 0; }
  __syncthreads();
  for (int i = t; i < NB; i += 256) {
    int cnt = gtile[gt + i];
    int gb = cnt ? atomicAdd(&bnextp[(size_t)(i * SUBS + sub) * 16], cnt) : 0;
    shift[i] = gb - loff[i];
  }
  __syncthreads();
  for (int e = e0 + t; e < e1; e += 256) {
    int c = col[e];
    int b = c >> 8;
    int pl = loff[b] + atomicAdd(&lc[b], 1);
    unsigned int wh = (unsigned int)__half_as_ushort(__float2half(w[e]));
    buf[pl] = make_int2(row[e] | ((c & 255) << 20), (int)((unsigned)b << 16 | wh));
  }
  __syncthreads();
  int total = e1 - e0;
  for (int i = t; i < total; i += 256) {
    int2 v = buf[i];
    int b = ((unsigned)v.y) >> 16;
    raw[shift[b] + i] = v;
  }
}

// Merged per-bucket counting sort (512 threads): offn/dinv + vfs scaling +
// scatter edat = u32 {r:20, q12(w*dinv[c]):12}. w decoded from raw.y low 16.
__global__ __launch_bounds__(512) void k_bsort(const int2* __restrict__ raw,
                                               const int* __restrict__ boff,
                                               const float* __restrict__ vf,
                                               unsigned int* __restrict__ edat,
                                               int* __restrict__ offn,
                                               float* __restrict__ dinv,
                                               float* __restrict__ vfs, int N) {
  __shared__ int cnt[256];
  __shared__ float wsum[256];
  __shared__ int s[256];
  __shared__ int pos[256];
  __shared__ float dl[256];
  int t = threadIdx.x, b = blockIdx.x;
  int e0 = boff[b * SUBS], e1 = boff[(b + 1) * SUBS];
  if (t < 256) { cnt[t] = 0; wsum[t] = 0.0f; }
  __syncthreads();
  for (int e = e0 + t; e < e1; e += 512) {
    int2 a = raw[e];
    int cl = ((unsigned)a.x) >> 20;
    unsigned short wh = (unsigned short)(a.y & 0xffff);
    atomicAdd(&cnt[cl], 1);
    atomicAdd(&wsum[cl], __half2float(*reinterpret_cast<__half*>(&wh)));
  }
  __syncthreads();
  int c = 0;
  if (t < 256) { c = cnt[t]; s[t] = c; }
  __syncthreads();
  for (int d = 1; d < 256; d <<= 1) {
    int v = (t < 256 && t >= d) ? s[t - d] : 0;
    __syncthreads();
    if (t < 256) s[t] += v;
    __syncthreads();
  }
  if (t < 256) {
    int excl = s[t] - c;
    float dv = rsqrtf(wsum[t] + 1.0f);
    int node = b * 256 + t;
    if (node < N) {
      dinv[node] = dv;
      offn[node] = e0 + excl;
#pragma unroll
      for (int f = 0; f < 6; ++f) vfs[node * 6 + f] = dv * vf[node * 6 + f];
    }
    pos[t] = e0 + excl;
    dl[t] = dv;
  }
  __syncthreads();
  for (int e = e0 + t; e < e1; e += 512) {
    int2 a = raw[e];
    int cl = ((unsigned)a.x) >> 20;
    unsigned short wh = (unsigned short)(a.y & 0xffff);
    float nrm = __half2float(*reinterpret_cast<__half*>(&wh)) * dl[cl];
    unsigned int q = ((unsigned int)__half_as_ushort(__float2half(nrm)) + 4u) >> 3;
    int p = atomicAdd(&pos[cl], 1);
    edat[p] = (unsigned int)(a.x & RMASK) | (q << 20);
  }
}

// Fused layer 1: 6-wide aggregation + dense 6->64 + sigmoid -> fp16 X.
// 8 lanes/node; after the gather, shfl-broadcast the 6 Sx values across the
// group; every lane computes 8 cols and writes one uint4 (16B, coalesced).
__global__ __launch_bounds__(256) void k_l1(const float* __restrict__ vfs,
                                            const float* __restrict__ dinv,
                                            const int* __restrict__ offn,
                                            const unsigned int* __restrict__ edat,
                                            const float* __restrict__ W1,
                                            const float* __restrict__ b1,
                                            __half* __restrict__ X, int N) {
  __shared__ float Wl[6 * 64];
  __shared__ float bl[64];
  int t = threadIdx.x;
  for (int i = t; i < 384; i += 256) Wl[i] = W1[i];
  if (t < 64) bl[t] = b1[t];
  __syncthreads();
  int g = t >> 3, f = t & 7;
  int node = blockIdx.x * 32 + g;
  if (node >= N) return;
  bool act = f < 6;
  float dc = dinv[node];
  float acc = act ? dc * vfs[node * 6 + f] : 0.0f;  // dinv^2*vf = dinv*vfs
  int e1 = offn[node + 1];
  for (int e = offn[node]; e < e1; ++e) {
    unsigned int a = edat[e];
    if (act) acc += q12f(a >> 20) * vfs[(a & RMASK) * 6 + f];
  }
  // broadcast Sx[0..5] across the 8-lane group
  int base = (t & 63) & ~7;
  float sx[6];
#pragma unroll
  for (int f2 = 0; f2 < 6; ++f2) sx[f2] = __shfl(acc, base + f2, 64);
  // this lane computes cols f*8 .. f*8+7
  int c0 = f * 8;
  __half2 o[4];
#pragma unroll
  for (int j = 0; j < 4; ++j) {
    float clo = bl[c0 + 2 * j];
    float chi = bl[c0 + 2 * j + 1];
#pragma unroll
    for (int f2 = 0; f2 < 6; ++f2) {
      clo += sx[f2] * Wl[f2 * 64 + c0 + 2 * j];
      chi += sx[f2] * Wl[f2 * 64 + c0 + 2 * j + 1];
    }
    o[j] = __floats2half2_rn(sigf(clo), sigf(chi));
  }
  uint4 ov = make_uint4(*reinterpret_cast<unsigned int*>(&o[0]),
                        *reinterpret_cast<unsigned int*>(&o[1]),
                        *reinterpret_cast<unsigned int*>(&o[2]),
                        *reinterpret_cast<unsigned int*>(&o[3]));
  *(uint4*)(X + (size_t)node * 64 + c0) = ov;
}

// Hq(e5m2) = dinv .* (X(half) @ W(f32)). Pack fused: half2 pair + 0x800080
// round, v_perm picks top bytes, one coalesced 4B store per thread per i.
__global__ __launch_bounds__(256, 3) void k_gemm64(const __half* __restrict__ Xin,
                                                   const float* __restrict__ W,
                                                   const float* __restrict__ dinv,
                                                   unsigned char* __restrict__ Hq, int N) {
  __shared__ float XT[64 * 65];
  __shared__ float Wl[64 * 64];
  int t = threadIdx.x;
  int n0 = blockIdx.x * 64;
#pragma unroll
  for (int i = 0; i < 4; ++i) {
    int idx = (i * 256 + t) * 4;
    *(float4*)&Wl[idx] = *(const float4*)&W[idx];
  }
#pragma unroll
  for (int i = 0; i < 2; ++i) {
    int idx = (i * 256 + t) * 8;
    int n = idx >> 6, k = idx & 63;
    int node = n0 + n;
    __half2 hv[4];
    if (node < N) {
      const __half2* src = (const __half2*)(Xin + (size_t)node * 64 + k);
      hv[0] = src[0]; hv[1] = src[1]; hv[2] = src[2]; hv[3] = src[3];
    } else {
      hv[0] = hv[1] = hv[2] = hv[3] = __floats2half2_rn(0.f, 0.f);
    }
#pragma unroll
    for (int j = 0; j < 4; ++j) {
      float2 f = __half22float2(hv[j]);
      XT[(k + 2 * j) * 65 + n] = f.x;
      XT[(k + 2 * j + 1) * 65 + n] = f.y;
    }
  }
  __syncthreads();
  int c0 = (t & 15) * 4;
  int nn = (t >> 4) * 4;
  float acc[4][4] = {{0.f}};
#pragma unroll 16
  for (int k = 0; k < 64; ++k) {
    float4 wv = *(const float4*)&Wl[k * 64 + c0];
    float xv[4];
#pragma unroll
    for (int i = 0; i < 4; ++i) xv[i] = XT[k * 65 + nn + i];
#pragma unroll
    for (int i = 0; i < 4; ++i) {
      acc[i][0] += xv[i] * wv.x;
      acc[i][1] += xv[i] * wv.y;
      acc[i][2] += xv[i] * wv.z;
      acc[i][3] += xv[i] * wv.w;
    }
  }
#pragma unroll
  for (int i = 0; i < 4; ++i) {
    int node = n0 + nn + i;
    if (node < N) {
      float dv = dinv[node];
      __half2 h01 = __floats2half2_rn(dv * acc[i][0], dv * acc[i][1]);
      __half2 h23 = __floats2half2_rn(dv * acc[i][2], dv * acc[i][3]);
      unsigned int r01 = *reinterpret_cast<unsigned int*>(&h01) + 0x00800080u;
      unsigned int r23 = *reinterpret_cast<unsigned int*>(&h23) + 0x00800080u;
      unsigned int packed = __builtin_amdgcn_perm(r23, r01, 0x07050301u);
      *(unsigned int*)(Hq + (size_t)node * 64 + c0) = packed;
    }
  }
}

// Quarter-wave-per-node CSC gather agg on e5m2 H'; lane owns feats {4l..4l+3}.
// v_perm expands 4 e5m2 bytes -> 2 half2; 2 pk_fma per edge.
// LAST: h5' = dinv * (x . W5).
template <bool LAST>
__global__ __launch_bounds__(256) void k_agg64(const unsigned char* __restrict__ Hq,
                                               const float* __restrict__ dinv,
                                               const int* __restrict__ offn,
                                               const unsigned int* __restrict__ edat,
                                               const float* __restrict__ b,
                                               const float* __restrict__ W5,
                                               __half* __restrict__ Xout,
                                               float* __restrict__ h5, int N) {
  const unsigned int* Hu = (const unsigned int*)Hq;  // [N][16] e5m2x4
  const unsigned int sel0 = 0x01040004u;  // {0, b0, 0, b1} from lo operand
  const unsigned int sel1 = 0x03040204u;  // {0, b2, 0, b3}
  int t = threadIdx.x;
  int l = t & 15;
  int qw = t >> 4;  // 16 quarter-waves per block
  int node = blockIdx.x * 16 + qw;
  if (node >= N) return;
  float di = dinv[node];
  unsigned int sh = Hu[(unsigned int)node * 16 + l];
  unsigned int sb0 = __builtin_amdgcn_perm(0u, sh, sel0);
  unsigned int sb1 = __builtin_amdgcn_perm(0u, sh, sel1);
  float2 f01 = __half22float2(*reinterpret_cast<__half2*>(&sb0));
  float2 f23 = __half22float2(*reinterpret_cast<__half2*>(&sb1));
  __half2 acc0 = __floats2half2_rn(di * f01.x, di * f01.y);
  __half2 acc1 = __floats2half2_rn(di * f23.x, di * f23.y);
  int e = offn[node], e1 = offn[node + 1];
  for (; e + 7 < e1; e += 8) {
    unsigned int a[8];
    unsigned int hv[8];
#pragma unroll
    for (int j = 0; j < 8; ++j) a[j] = edat[e + j];
#pragma unroll
    for (int j = 0; j < 8; ++j) hv[j] = Hu[(a[j] & RMASK) * 16u + l];
#pragma unroll
    for (int j = 0; j < 8; ++j) {
      unsigned int nmb = ((a[j] >> 20) << 3) * 0x10001u;  // {nm,nm} half bits
      unsigned int hb0 = __builtin_amdgcn_perm(0u, hv[j], sel0);
      unsigned int hb1 = __builtin_amdgcn_perm(0u, hv[j], sel1);
      acc0 = __hfma2(*reinterpret_cast<__half2*>(&nmb),
                     *reinterpret_cast<__half2*>(&hb0), acc0);
      acc1 = __hfma2(*reinterpret_cast<__half2*>(&nmb),
                     *reinterpret_cast<__half2*>(&hb1), acc1);
    }
  }
  for (; e < e1; ++e) {
    unsigned int a = edat[e];
    unsigned int hv = Hu[(a & RMASK) * 16u + l];
    unsigned int nmb = ((a >> 20) << 3) * 0x10001u;
    unsigned int hb0 = __builtin_amdgcn_perm(0u, hv, sel0);
    unsigned int hb1 = __builtin_amdgcn_perm(0u, hv, sel1);
    acc0 = __hfma2(*reinterpret_cast<__half2*>(&nmb),
                   *reinterpret_cast<__half2*>(&hb0), acc0);
    acc1 = __hfma2(*reinterpret_cast<__half2*>(&nmb),
                   *reinterpret_cast<__half2*>(&hb1), acc1);
  }
  float2 a01 = __half22float2(acc0);
  float2 a23 = __half22float2(acc1);
  float4 bb = ((const float4*)b)[l];
  float x0 = sigf(a01.x + bb.x);
  float x1 = sigf(a01.y + bb.y);
  float x2 = sigf(a23.x + bb.z);
  float x3 = sigf(a23.y + bb.w);
  if (LAST) {
    float4 w5 = ((const float4*)W5)[l];
    float v = x0 * w5.x + x1 * w5.y + x2 * w5.z + x3 * w5.w;
#pragma unroll
    for (int d = 8; d; d >>= 1) v += __shfl_xor(v, d);  // within quarter-wave
    if (l == 0) h5[node] = di * v;  // h5' = dinv * (x . W5)
  } else {
    __half2 o0 = __floats2half2_rn(x0, x1);
    __half2 o1 = __floats2half2_rn(x2, x3);
    ((uint2*)(Xout + (size_t)node * 64))[l] =
        make_uint2(*reinterpret_cast<unsigned int*>(&o0),
                   *reinterpret_cast<unsigned int*>(&o1));
  }
}

// scalar CSC aggregation on h5' + sigmoid + per-block partial sum
__global__ __launch_bounds__(256) void k_agg5(const float* __restrict__ h5,
                                              const float* __restrict__ dinv,
                                              const int* __restrict__ offn,
                                              const unsigned int* __restrict__ edat,
                                              const float* __restrict__ b5,
                                              float* __restrict__ partials, int N) {
  int n = blockIdx.x * 256 + threadIdx.x;
  float sig = 0.0f;
  if (n < N) {
    float di = dinv[n];
    float acc = di * h5[n];  // dinv^2 * (x.W5) = dinv * h5'
    int e1 = offn[n + 1];
    for (int e = offn[n]; e < e1; ++e) {
      unsigned int a = edat[e];
      acc += q12f(a >> 20) * h5[a & RMASK];
    }
    sig = sigf(acc + b5[0]);
  }
#pragma unroll
  for (int d = 32; d; d >>= 1) sig += __shfl_xor(sig, d);
  __shared__ float ws[4];
  int lane = threadIdx.x & 63, wid = threadIdx.x >> 6;
  if (lane == 0) ws[wid] = sig;
  __syncthreads();
  if (threadIdx.x == 0) partials[blockIdx.x] = ws[0] + ws[1] + ws[2] + ws[3];
}

__global__ __launch_bounds__(512) void k_final(const float* __restrict__ partials,
                                               float* __restrict__ out, int nb,
                                               float invN) {
  float v = 0.0f;
  for (int i = threadIdx.x; i < nb; i += 512) v += partials[i];
#pragma unroll
  for (int d = 32; d; d >>= 1) v += __shfl_xor(v, d);
  __shared__ float ws[8];
  int lane = threadIdx.x & 63, wid = threadIdx.x >> 6;
  if (lane == 0) ws[wid] = v;
  __syncthreads();
  if (threadIdx.x == 0) {
    float s = 0.0f;
    for (int i = 0; i < 8; ++i) s += ws[i];
    out[0] = s * invN;
  }
}

extern "C" void kernel_launch(void* const* d_in, const int* in_sizes, int n_in,
                              void* d_out, int out_size, void* d_ws, size_t ws_size,
                              hipStream_t stream) {
  const float* vf = (const float*)d_in[0];
  const int* edges = (const int*)d_in[1];
  const float* w = (const float*)d_in[2];
  const float* W1 = (const float*)d_in[3];
  const float* b1 = (const float*)d_in[4];
  const float* W2 = (const float*)d_in[5];
  const float* b2 = (const float*)d_in[6];
  const float* W3 = (const float*)d_in[7];
  const float* b3 = (const float*)d_in[8];
  const float* W4 = (const float*)d_in[9];
  const float* b4 = (const float*)d_in[10];
  const float* W5 = (const float*)d_in[11];
  const float* b5 = (const float*)d_in[12];
  float* out = (float*)d_out;

  const int N = in_sizes[0] / 6;
  const int E = in_sizes[2];
  const int* row = edges;
  const int* col = edges + E;
  const int NB = (N + 255) >> 8;
  const int M = NB * SUBS;
  const int tiles = (E + TILE - 1) >> TILE_SHIFT;

  size_t o = 0;
  auto carve = [&](size_t bytes) -> void* {
    void* p = (char*)d_ws + o;
    o += (bytes + 255) & ~(size_t)255;
    return p;
  };
  __half* X = (__half*)carve((size_t)N * 64 * 2);
  int2* raw = (int2*)carve((size_t)E * 8);
  unsigned char* Hq = (unsigned char*)carve((size_t)N * 64);  // e5m2 H'
  unsigned int* edat = (unsigned int*)carve((size_t)E * 4);   // {r:20, q12:12}
  float* vfs = (float*)carve((size_t)N * 6 * 4);
  float* dinv = (float*)carve((size_t)N * 4);
  int* boff = (int*)carve((size_t)(M + 1) * 4);
  int* bnextp = (int*)carve((size_t)M * 16 * 4);  // line-padded cursors
  int* gcnt = (int*)carve((size_t)M * 4);
  int* gtile = (int*)carve((size_t)tiles * NB * 4);
  int* offn = (int*)carve((size_t)(N + 1) * 4);
  float* h5 = (float*)carve((size_t)N * 4);
  const int nb5 = (N + 255) / 256;
  float* partials = (float*)carve((size_t)nb5 * 4);

  hipMemsetAsync(gcnt, 0, (size_t)M * 4, stream);

  k_count<<<tiles, 256, 0, stream>>>(col, gcnt, gtile, E, NB);
  k_bscan<<<1, 1024, 0, stream>>>(gcnt, boff, bnextp, offn, M, N);
  k_tscatter<<<tiles, 256, 0, stream>>>(row, col, w, gtile, bnextp, raw, E, NB);
  k_bsort<<<NB, 512, 0, stream>>>(raw, boff, vf, edat, offn, dinv, vfs, N);

  // layer 1 fused: aggregate (D=6) + dense 6->64 + sigmoid (fp16 X out)
  k_l1<<<(N + 31) / 32, 256, 0, stream>>>(vfs, dinv, offn, edat, W1, b1, X, N);

  // layers 2-4: gemm64 (fused e5m2 pack) -> agg64 (fp8 gather)
  const int nbA = (N + 15) / 16;
  k_gemm64<<<(N + 63) / 64, 256, 0, stream>>>(X, W2, dinv, Hq, N);
  k_agg64<false><<<nbA, 256, 0, stream>>>(Hq, dinv, offn, edat, b2, W5, X, h5, N);
  k_gemm64<<<(N + 63) / 64, 256, 0, stream>>>(X, W3, dinv, Hq, N);
  k_agg64<false><<<nbA, 256, 0, stream>>>(Hq, dinv, offn, edat, b3, W5, X, h5, N);
  k_gemm64<<<(N + 63) / 64, 256, 0, stream>>>(X, W4, dinv, Hq, N);
  k_agg64<true><<<nbA, 256, 0, stream>>>(Hq, dinv, offn, edat, b4, W5, X, h5, N);

  // layer 5: scalar aggregation + mean
  k_agg5<<<nb5, 256, 0, stream>>>(h5, dinv, offn, edat, b5, partials, N);
  k_final<<<1, 512, 0, stream>>>(partials, out, nb5, 1.0f / (float)N);
}

// Round 27
// 359.853 us; speedup vs baseline: 1.4539x; 1.0469x over previous
//
#include <hip/hip_runtime.h>
#include <hip/hip_fp16.h>
#include <math.h>

// GCN 5-layer on MI355X — round 27: edge-parallel k_l1.
// R26 profile: k_l1 is the top dispatch (49us, 637 GB/s, VALU 27%) —
// latency-bound because 8 lanes serially walk the whole edge list with
// 8x-redundant edat loads. Fix: lane f takes edges e0+f, e0+f+8, ...; keeps
// all 6 feature sums in registers (1 edat load + 3 float2 gathers + 6 FMA
// per edge); 3-step shfl_xor reduces within the 8-lane group; all lanes then
// hold Sx and go straight to the 8-column sigmoid output (broadcast gone).
// Rest identical to the measured 376.7us kernel (R23 design).

__device__ __forceinline__ float sigf(float x) { return 1.0f / (1.0f + expf(-x)); }

// decode 12-bit e5m7 (positive) -> float
__device__ __forceinline__ float q12f(unsigned int q) {
  unsigned short hb = (unsigned short)(q << 3);
  __half h = *reinterpret_cast<__half*>(&hb);
  return __half2float(h);
}

#define RMASK 0xFFFFF
#define SUBS 8            // cursor streams per bucket (blockIdx & 7)
#define TILE_SHIFT 12     // 4096 edges per tile
#define TILE (1 << TILE_SHIFT)
#define NBMAX 512

__global__ __launch_bounds__(256) void k_count(const int* __restrict__ col,
                                               int* __restrict__ gcnt,
                                               int* __restrict__ gtile, int E, int NB) {
  __shared__ int lc[NBMAX];
  int t = threadIdx.x;
  for (int i = t; i < NB; i += 256) lc[i] = 0;
  __syncthreads();
  int base = blockIdx.x << TILE_SHIFT;
  int sub = blockIdx.x & (SUBS - 1);
  int hi = base + TILE; if (hi > E) hi = E;
  for (int e = base + t; e < hi; e += 256) atomicAdd(&lc[col[e] >> 8], 1);
  __syncthreads();
  size_t gt = (size_t)blockIdx.x * NB;
  for (int i = t; i < NB; i += 256) {
    int c = lc[i];
    gtile[gt + i] = c;
    if (c) atomicAdd(&gcnt[i * SUBS + sub], c);
  }
}

// scan M = NB*SUBS counters; cursors line-padded (16 ints apart)
__global__ __launch_bounds__(1024) void k_bscan(const int* __restrict__ gcnt,
                                                int* __restrict__ boff,
                                                int* __restrict__ bnextp,
                                                int* __restrict__ offn, int M, int N) {
  __shared__ int s[1024];
  int t = threadIdx.x;
  int chunk = (M + 1023) / 1024;
  int lo = t * chunk; if (lo > M) lo = M;
  int hi = lo + chunk; if (hi > M) hi = M;
  int sum = 0;
  for (int i = lo; i < hi; ++i) sum += gcnt[i];
  s[t] = sum;
  __syncthreads();
  for (int d = 1; d < 1024; d <<= 1) {
    int v = (t >= d) ? s[t - d] : 0;
    __syncthreads();
    s[t] += v;
    __syncthreads();
  }
  int run = s[t] - sum;
  for (int i = lo; i < hi; ++i) {
    boff[i] = run;
    bnextp[(size_t)i * 16] = run;
    run += gcnt[i];
  }
  if (t == 1023) { boff[M] = s[1023]; offn[N] = s[1023]; }
}

// LDS-staged tile scatter: sort tile into LDS by bucket, then coalesced runs.
// buf.y = (bucket << 16) | fp16bits(w); bsort decodes w from low 16.
__global__ __launch_bounds__(256) void k_tscatter(const int* __restrict__ row,
                                                  const int* __restrict__ col,
                                                  const float* __restrict__ w,
                                                  const int* __restrict__ gtile,
                                                  int* __restrict__ bnextp,
                                                  int2* __restrict__ raw, int E, int NB) {
  __shared__ int2 buf[TILE];            // 32 KB
  __shared__ int loff[NBMAX];
  __shared__ int lc[NBMAX];
  __shared__ int shift[NBMAX];
  __shared__ int sc[256];
  int t = threadIdx.x;
  int e0 = blockIdx.x << TILE_SHIFT;
  int sub = blockIdx.x & (SUBS - 1);
  int e1 = e0 + TILE; if (e1 > E) e1 = E;
  size_t gt = (size_t)blockIdx.x * NB;
  int c0 = (2 * t < NB) ? gtile[gt + 2 * t] : 0;
  int c1 = (2 * t + 1 < NB) ? gtile[gt + 2 * t + 1] : 0;
  sc[t] = c0 + c1;
  __syncthreads();
  for (int d = 1; d < 256; d <<= 1) {
    int v = (t >= d) ? sc[t - d] : 0;
    __syncthreads();
    sc[t] += v;
    __syncthreads();
  }
  int excl = sc[t] - (c0 + c1);
  if (2 * t < NB) { loff[2 * t] = excl; lc[2 * t] = 0; }
  if (2 * t + 1 < NB) { loff[2 * t + 1] = excl + c0; lc[2 * t + 1] = 0; }
  __syncthreads();
  for (int i = t; i < NB; i += 256) {
    int cnt = gtile[gt + i];
    int gb = cnt ? atomicAdd(&bnextp[(size_t)(i * SUBS + sub) * 16], cnt) : 0;
    shift[i] = gb - loff[i];
  }
  __syncthreads();
  for (int e = e0 + t; e < e1; e += 256) {
    int c = col[e];
    int b = c >> 8;
    int pl = loff[b] + atomicAdd(&lc[b], 1);
    unsigned int wh = (unsigned int)__half_as_ushort(__float2half(w[e]));
    buf[pl] = make_int2(row[e] | ((c & 255) << 20), (int)((unsigned)b << 16 | wh));
  }
  __syncthreads();
  int total = e1 - e0;
  for (int i = t; i < total; i += 256) {
    int2 v = buf[i];
    int b = ((unsigned)v.y) >> 16;
    raw[shift[b] + i] = v;
  }
}

// Merged per-bucket counting sort (512 threads): offn/dinv + vfs scaling +
// scatter edat = u32 {r:20, q12(w*dinv[c]):12}. w decoded from raw.y low 16.
__global__ __launch_bounds__(512) void k_bsort(const int2* __restrict__ raw,
                                               const int* __restrict__ boff,
                                               const float* __restrict__ vf,
                                               unsigned int* __restrict__ edat,
                                               int* __restrict__ offn,
                                               float* __restrict__ dinv,
                                               float* __restrict__ vfs, int N) {
  __shared__ int cnt[256];
  __shared__ float wsum[256];
  __shared__ int s[256];
  __shared__ int pos[256];
  __shared__ float dl[256];
  int t = threadIdx.x, b = blockIdx.x;
  int e0 = boff[b * SUBS], e1 = boff[(b + 1) * SUBS];
  if (t < 256) { cnt[t] = 0; wsum[t] = 0.0f; }
  __syncthreads();
  for (int e = e0 + t; e < e1; e += 512) {
    int2 a = raw[e];
    int cl = ((unsigned)a.x) >> 20;
    unsigned short wh = (unsigned short)(a.y & 0xffff);
    atomicAdd(&cnt[cl], 1);
    atomicAdd(&wsum[cl], __half2float(*reinterpret_cast<__half*>(&wh)));
  }
  __syncthreads();
  int c = 0;
  if (t < 256) { c = cnt[t]; s[t] = c; }
  __syncthreads();
  for (int d = 1; d < 256; d <<= 1) {
    int v = (t < 256 && t >= d) ? s[t - d] : 0;
    __syncthreads();
    if (t < 256) s[t] += v;
    __syncthreads();
  }
  if (t < 256) {
    int excl = s[t] - c;
    float dv = rsqrtf(wsum[t] + 1.0f);
    int node = b * 256 + t;
    if (node < N) {
      dinv[node] = dv;
      offn[node] = e0 + excl;
#pragma unroll
      for (int f = 0; f < 6; ++f) vfs[node * 6 + f] = dv * vf[node * 6 + f];
    }
    pos[t] = e0 + excl;
    dl[t] = dv;
  }
  __syncthreads();
  for (int e = e0 + t; e < e1; e += 512) {
    int2 a = raw[e];
    int cl = ((unsigned)a.x) >> 20;
    unsigned short wh = (unsigned short)(a.y & 0xffff);
    float nrm = __half2float(*reinterpret_cast<__half*>(&wh)) * dl[cl];
    unsigned int q = ((unsigned int)__half_as_ushort(__float2half(nrm)) + 4u) >> 3;
    int p = atomicAdd(&pos[cl], 1);
    edat[p] = (unsigned int)(a.x & RMASK) | (q << 20);
  }
}

// Fused layer 1, edge-parallel: lane f of each 8-lane group takes edges
// e0+f, e0+f+8, ...; keeps 6 feature sums in registers (3 float2 gathers per
// edge); shfl_xor tree (d=1,2,4) reduces within the group; then every lane
// computes 8 sigmoid cols from LDS W1/b1 and writes one uint4 of fp16 X.
__global__ __launch_bounds__(256) void k_l1(const float* __restrict__ vfs,
                                            const float* __restrict__ dinv,
                                            const int* __restrict__ offn,
                                            const unsigned int* __restrict__ edat,
                                            const float* __restrict__ W1,
                                            const float* __restrict__ b1,
                                            __half* __restrict__ X, int N) {
  __shared__ float Wl[6 * 64];
  __shared__ float bl[64];
  int t = threadIdx.x;
  for (int i = t; i < 384; i += 256) Wl[i] = W1[i];
  if (t < 64) bl[t] = b1[t];
  __syncthreads();
  int g = t >> 3, f = t & 7;
  int node = blockIdx.x * 32 + g;
  if (node >= N) return;
  float a0 = 0.f, a1 = 0.f, a2 = 0.f, a3 = 0.f, a4 = 0.f, a5 = 0.f;
  int e0 = offn[node], e1 = offn[node + 1];
  for (int e = e0 + f; e < e1; e += 8) {
    unsigned int a = edat[e];
    float nm = q12f(a >> 20);
    const float2* rp = (const float2*)(vfs + (size_t)(a & RMASK) * 6);
    float2 r0 = rp[0], r1 = rp[1], r2 = rp[2];
    a0 += nm * r0.x; a1 += nm * r0.y;
    a2 += nm * r1.x; a3 += nm * r1.y;
    a4 += nm * r2.x; a5 += nm * r2.y;
  }
#pragma unroll
  for (int d = 1; d < 8; d <<= 1) {
    a0 += __shfl_xor(a0, d);
    a1 += __shfl_xor(a1, d);
    a2 += __shfl_xor(a2, d);
    a3 += __shfl_xor(a3, d);
    a4 += __shfl_xor(a4, d);
    a5 += __shfl_xor(a5, d);
  }
  // self term: dinv^2*vf = dinv*vfs
  float dc = dinv[node];
  const float2* sp = (const float2*)(vfs + (size_t)node * 6);
  float2 s0 = sp[0], s1 = sp[1], s2 = sp[2];
  float sx[6];
  sx[0] = a0 + dc * s0.x; sx[1] = a1 + dc * s0.y;
  sx[2] = a2 + dc * s1.x; sx[3] = a3 + dc * s1.y;
  sx[4] = a4 + dc * s2.x; sx[5] = a5 + dc * s2.y;
  // this lane computes cols f*8 .. f*8+7
  int c0 = f * 8;
  __half2 o[4];
#pragma unroll
  for (int j = 0; j < 4; ++j) {
    float clo = bl[c0 + 2 * j];
    float chi = bl[c0 + 2 * j + 1];
#pragma unroll
    for (int f2 = 0; f2 < 6; ++f2) {
      clo += sx[f2] * Wl[f2 * 64 + c0 + 2 * j];
      chi += sx[f2] * Wl[f2 * 64 + c0 + 2 * j + 1];
    }
    o[j] = __floats2half2_rn(sigf(clo), sigf(chi));
  }
  uint4 ov = make_uint4(*reinterpret_cast<unsigned int*>(&o[0]),
                        *reinterpret_cast<unsigned int*>(&o[1]),
                        *reinterpret_cast<unsigned int*>(&o[2]),
                        *reinterpret_cast<unsigned int*>(&o[3]));
  *(uint4*)(X + (size_t)node * 64 + c0) = ov;
}

// Hq(e5m2) = dinv .* (X(half) @ W(f32)). Pack fused: half2 pair + 0x800080
// round, v_perm picks top bytes, one coalesced 4B store per thread per i.
__global__ __launch_bounds__(256, 3) void k_gemm64(const __half* __restrict__ Xin,
                                                   const float* __restrict__ W,
                                                   const float* __restrict__ dinv,
                                                   unsigned char* __restrict__ Hq, int N) {
  __shared__ float XT[64 * 65];
  __shared__ float Wl[64 * 64];
  int t = threadIdx.x;
  int n0 = blockIdx.x * 64;
#pragma unroll
  for (int i = 0; i < 4; ++i) {
    int idx = (i * 256 + t) * 4;
    *(float4*)&Wl[idx] = *(const float4*)&W[idx];
  }
#pragma unroll
  for (int i = 0; i < 2; ++i) {
    int idx = (i * 256 + t) * 8;
    int n = idx >> 6, k = idx & 63;
    int node = n0 + n;
    __half2 hv[4];
    if (node < N) {
      const __half2* src = (const __half2*)(Xin + (size_t)node * 64 + k);
      hv[0] = src[0]; hv[1] = src[1]; hv[2] = src[2]; hv[3] = src[3];
    } else {
      hv[0] = hv[1] = hv[2] = hv[3] = __floats2half2_rn(0.f, 0.f);
    }
#pragma unroll
    for (int j = 0; j < 4; ++j) {
      float2 f = __half22float2(hv[j]);
      XT[(k + 2 * j) * 65 + n] = f.x;
      XT[(k + 2 * j + 1) * 65 + n] = f.y;
    }
  }
  __syncthreads();
  int c0 = (t & 15) * 4;
  int nn = (t >> 4) * 4;
  float acc[4][4] = {{0.f}};
#pragma unroll 16
  for (int k = 0; k < 64; ++k) {
    float4 wv = *(const float4*)&Wl[k * 64 + c0];
    float xv[4];
#pragma unroll
    for (int i = 0; i < 4; ++i) xv[i] = XT[k * 65 + nn + i];
#pragma unroll
    for (int i = 0; i < 4; ++i) {
      acc[i][0] += xv[i] * wv.x;
      acc[i][1] += xv[i] * wv.y;
      acc[i][2] += xv[i] * wv.z;
      acc[i][3] += xv[i] * wv.w;
    }
  }
#pragma unroll
  for (int i = 0; i < 4; ++i) {
    int node = n0 + nn + i;
    if (node < N) {
      float dv = dinv[node];
      __half2 h01 = __floats2half2_rn(dv * acc[i][0], dv * acc[i][1]);
      __half2 h23 = __floats2half2_rn(dv * acc[i][2], dv * acc[i][3]);
      unsigned int r01 = *reinterpret_cast<unsigned int*>(&h01) + 0x00800080u;
      unsigned int r23 = *reinterpret_cast<unsigned int*>(&h23) + 0x00800080u;
      unsigned int packed = __builtin_amdgcn_perm(r23, r01, 0x07050301u);
      *(unsigned int*)(Hq + (size_t)node * 64 + c0) = packed;
    }
  }
}

// Quarter-wave-per-node CSC gather agg on e5m2 H'; lane owns feats {4l..4l+3}.
// v_perm expands 4 e5m2 bytes -> 2 half2; 2 pk_fma per edge.
// LAST: h5' = dinv * (x . W5).
template <bool LAST>
__global__ __launch_bounds__(256) void k_agg64(const unsigned char* __restrict__ Hq,
                                               const float* __restrict__ dinv,
                                               const int* __restrict__ offn,
                                               const unsigned int* __restrict__ edat,
                                               const float* __restrict__ b,
                                               const float* __restrict__ W5,
                                               __half* __restrict__ Xout,
                                               float* __restrict__ h5, int N) {
  const unsigned int* Hu = (const unsigned int*)Hq;  // [N][16] e5m2x4
  const unsigned int sel0 = 0x01040004u;  // {0, b0, 0, b1} from lo operand
  const unsigned int sel1 = 0x03040204u;  // {0, b2, 0, b3}
  int t = threadIdx.x;
  int l = t & 15;
  int qw = t >> 4;  // 16 quarter-waves per block
  int node = blockIdx.x * 16 + qw;
  if (node >= N) return;
  float di = dinv[node];
  unsigned int sh = Hu[(unsigned int)node * 16 + l];
  unsigned int sb0 = __builtin_amdgcn_perm(0u, sh, sel0);
  unsigned int sb1 = __builtin_amdgcn_perm(0u, sh, sel1);
  float2 f01 = __half22float2(*reinterpret_cast<__half2*>(&sb0));
  float2 f23 = __half22float2(*reinterpret_cast<__half2*>(&sb1));
  __half2 acc0 = __floats2half2_rn(di * f01.x, di * f01.y);
  __half2 acc1 = __floats2half2_rn(di * f23.x, di * f23.y);
  int e = offn[node], e1 = offn[node + 1];
  for (; e + 7 < e1; e += 8) {
    unsigned int a[8];
    unsigned int hv[8];
#pragma unroll
    for (int j = 0; j < 8; ++j) a[j] = edat[e + j];
#pragma unroll
    for (int j = 0; j < 8; ++j) hv[j] = Hu[(a[j] & RMASK) * 16u + l];
#pragma unroll
    for (int j = 0; j < 8; ++j) {
      unsigned int nmb = ((a[j] >> 20) << 3) * 0x10001u;  // {nm,nm} half bits
      unsigned int hb0 = __builtin_amdgcn_perm(0u, hv[j], sel0);
      unsigned int hb1 = __builtin_amdgcn_perm(0u, hv[j], sel1);
      acc0 = __hfma2(*reinterpret_cast<__half2*>(&nmb),
                     *reinterpret_cast<__half2*>(&hb0), acc0);
      acc1 = __hfma2(*reinterpret_cast<__half2*>(&nmb),
                     *reinterpret_cast<__half2*>(&hb1), acc1);
    }
  }
  for (; e < e1; ++e) {
    unsigned int a = edat[e];
    unsigned int hv = Hu[(a & RMASK) * 16u + l];
    unsigned int nmb = ((a >> 20) << 3) * 0x10001u;
    unsigned int hb0 = __builtin_amdgcn_perm(0u, hv, sel0);
    unsigned int hb1 = __builtin_amdgcn_perm(0u, hv, sel1);
    acc0 = __hfma2(*reinterpret_cast<__half2*>(&nmb),
                   *reinterpret_cast<__half2*>(&hb0), acc0);
    acc1 = __hfma2(*reinterpret_cast<__half2*>(&nmb),
                   *reinterpret_cast<__half2*>(&hb1), acc1);
  }
  float2 a01 = __half22float2(acc0);
  float2 a23 = __half22float2(acc1);
  float4 bb = ((const float4*)b)[l];
  float x0 = sigf(a01.x + bb.x);
  float x1 = sigf(a01.y + bb.y);
  float x2 = sigf(a23.x + bb.z);
  float x3 = sigf(a23.y + bb.w);
  if (LAST) {
    float4 w5 = ((const float4*)W5)[l];
    float v = x0 * w5.x + x1 * w5.y + x2 * w5.z + x3 * w5.w;
#pragma unroll
    for (int d = 8; d; d >>= 1) v += __shfl_xor(v, d);  // within quarter-wave
    if (l == 0) h5[node] = di * v;  // h5' = dinv * (x . W5)
  } else {
    __half2 o0 = __floats2half2_rn(x0, x1);
    __half2 o1 = __floats2half2_rn(x2, x3);
    ((uint2*)(Xout + (size_t)node * 64))[l] =
        make_uint2(*reinterpret_cast<unsigned int*>(&o0),
                   *reinterpret_cast<unsigned int*>(&o1));
  }
}

// scalar CSC aggregation on h5' + sigmoid + per-block partial sum
__global__ __launch_bounds__(256) void k_agg5(const float* __restrict__ h5,
                                              const float* __restrict__ dinv,
                                              const int* __restrict__ offn,
                                              const unsigned int* __restrict__ edat,
                                              const float* __restrict__ b5,
                                              float* __restrict__ partials, int N) {
  int n = blockIdx.x * 256 + threadIdx.x;
  float sig = 0.0f;
  if (n < N) {
    float di = dinv[n];
    float acc = di * h5[n];  // dinv^2 * (x.W5) = dinv * h5'
    int e1 = offn[n + 1];
    for (int e = offn[n]; e < e1; ++e) {
      unsigned int a = edat[e];
      acc += q12f(a >> 20) * h5[a & RMASK];
    }
    sig = sigf(acc + b5[0]);
  }
#pragma unroll
  for (int d = 32; d; d >>= 1) sig += __shfl_xor(sig, d);
  __shared__ float ws[4];
  int lane = threadIdx.x & 63, wid = threadIdx.x >> 6;
  if (lane == 0) ws[wid] = sig;
  __syncthreads();
  if (threadIdx.x == 0) partials[blockIdx.x] = ws[0] + ws[1] + ws[2] + ws[3];
}

__global__ __launch_bounds__(512) void k_final(const float* __restrict__ partials,
                                               float* __restrict__ out, int nb,
                                               float invN) {
  float v = 0.0f;
  for (int i = threadIdx.x; i < nb; i += 512) v += partials[i];
#pragma unroll
  for (int d = 32; d; d >>= 1) v += __shfl_xor(v, d);
  __shared__ float ws[8];
  int lane = threadIdx.x & 63, wid = threadIdx.x >> 6;
  if (lane == 0) ws[wid] = v;
  __syncthreads();
  if (threadIdx.x == 0) {
    float s = 0.0f;
    for (int i = 0; i < 8; ++i) s += ws[i];
    out[0] = s * invN;
  }
}

extern "C" void kernel_launch(void* const* d_in, const int* in_sizes, int n_in,
                              void* d_out, int out_size, void* d_ws, size_t ws_size,
                              hipStream_t stream) {
  const float* vf = (const float*)d_in[0];
  const int* edges = (const int*)d_in[1];
  const float* w = (const float*)d_in[2];
  const float* W1 = (const float*)d_in[3];
  const float* b1 = (const float*)d_in[4];
  const float* W2 = (const float*)d_in[5];
  const float* b2 = (const float*)d_in[6];
  const float* W3 = (const float*)d_in[7];
  const float* b3 = (const float*)d_in[8];
  const float* W4 = (const float*)d_in[9];
  const float* b4 = (const float*)d_in[10];
  const float* W5 = (const float*)d_in[11];
  const float* b5 = (const float*)d_in[12];
  float* out = (float*)d_out;

  const int N = in_sizes[0] / 6;
  const int E = in_sizes[2];
  const int* row = edges;
  const int* col = edges + E;
  const int NB = (N + 255) >> 8;
  const int M = NB * SUBS;
  const int tiles = (E + TILE - 1) >> TILE_SHIFT;

  size_t o = 0;
  auto carve = [&](size_t bytes) -> void* {
    void* p = (char*)d_ws + o;
    o += (bytes + 255) & ~(size_t)255;
    return p;
  };
  __half* X = (__half*)carve((size_t)N * 64 * 2);
  int2* raw = (int2*)carve((size_t)E * 8);
  unsigned char* Hq = (unsigned char*)carve((size_t)N * 64);  // e5m2 H'
  unsigned int* edat = (unsigned int*)carve((size_t)E * 4);   // {r:20, q12:12}
  float* vfs = (float*)carve((size_t)N * 6 * 4);
  float* dinv = (float*)carve((size_t)N * 4);
  int* boff = (int*)carve((size_t)(M + 1) * 4);
  int* bnextp = (int*)carve((size_t)M * 16 * 4);  // line-padded cursors
  int* gcnt = (int*)carve((size_t)M * 4);
  int* gtile = (int*)carve((size_t)tiles * NB * 4);
  int* offn = (int*)carve((size_t)(N + 1) * 4);
  float* h5 = (float*)carve((size_t)N * 4);
  const int nb5 = (N + 255) / 256;
  float* partials = (float*)carve((size_t)nb5 * 4);

  hipMemsetAsync(gcnt, 0, (size_t)M * 4, stream);

  k_count<<<tiles, 256, 0, stream>>>(col, gcnt, gtile, E, NB);
  k_bscan<<<1, 1024, 0, stream>>>(gcnt, boff, bnextp, offn, M, N);
  k_tscatter<<<tiles, 256, 0, stream>>>(row, col, w, gtile, bnextp, raw, E, NB);
  k_bsort<<<NB, 512, 0, stream>>>(raw, boff, vf, edat, offn, dinv, vfs, N);

  // layer 1 fused: edge-parallel aggregate (D=6) + dense 6->64 + sigmoid
  k_l1<<<(N + 31) / 32, 256, 0, stream>>>(vfs, dinv, offn, edat, W1, b1, X, N);

  // layers 2-4: gemm64 (fused e5m2 pack) -> agg64 (fp8 gather)
  const int nbA = (N + 15) / 16;
  k_gemm64<<<(N + 63) / 64, 256, 0, stream>>>(X, W2, dinv, Hq, N);
  k_agg64<false><<<nbA, 256, 0, stream>>>(Hq, dinv, offn, edat, b2, W5, X, h5, N);
  k_gemm64<<<(N + 63) / 64, 256, 0, stream>>>(X, W3, dinv, Hq, N);
  k_agg64<false><<<nbA, 256, 0, stream>>>(Hq, dinv, offn, edat, b3, W5, X, h5, N);
  k_gemm64<<<(N + 63) / 64, 256, 0, stream>>>(X, W4, dinv, Hq, N);
  k_agg64<true><<<nbA, 256, 0, stream>>>(Hq, dinv, offn, edat, b4, W5, X, h5, N);

  // layer 5: scalar aggregation + mean
  k_agg5<<<nb5, 256, 0, stream>>>(h5, dinv, offn, edat, b5, partials, N);
  k_final<<<1, 512, 0, stream>>>(partials, out, nb5, 1.0f / (float)N);
}